// Round 7
// baseline (155.251 us; speedup 1.0000x reference)
//
#include <hip/hip_runtime.h>
#include <hip/hip_bf16.h>

#define BATCH 8
#define LTOK 1280
#define DIMC 192
#define HEADS 6
#define KD 32
#define HID 768
#define NROWS (BATCH*LTOK)   // 10240

typedef short s16x8 __attribute__((ext_vector_type(8)));
typedef float f32x4 __attribute__((ext_vector_type(4)));
typedef unsigned short u16;

// q pre-scale: 32^-0.5 * log2(e)  (softmax runs in exp2 domain)
#define QS (0.17677669529663687f * 1.4426950408889634f)
#define L2E 1.4426950408889634f

__device__ __forceinline__ u16 f2bf(float x) {
    unsigned u = __float_as_uint(x);
    u = (u + 0x7FFFu + ((u >> 16) & 1u)) >> 16;
    return (u16)u;
}
__device__ __forceinline__ float bflo(unsigned u) { return __uint_as_float(u << 16); }
__device__ __forceinline__ float bfhi(unsigned u) { return __uint_as_float(u & 0xffff0000u); }
__device__ __forceinline__ float fexp2(float x) { float r; asm("v_exp_f32 %0, %1" : "=v"(r) : "v"(x)); return r; }
__device__ __forceinline__ float frcp(float x)  { float r; asm("v_rcp_f32 %0, %1" : "=v"(r) : "v"(x)); return r; }

// ------- Preprocess: gamma-scaled weight transpose + bias-fold + bias matrix
// blocks [0,1728): W[K][N] f32 -> Wt[N][K] bf16 (x gamma[k] for wqkv/w1)
// blocks [1728,3328): bm[h][n][m] = bf16(tab*log2e)
// blocks [3328,3349): biasf[n] = b[n] + sum_k beta[k] * W[k][n]
__global__ __launch_bounds__(256) void pre_kernel(const float* w0, const float* w1,
                                                  const float* w2, const float* w3,
                                                  u16* o0, u16* o1, u16* o2, u16* o3,
                                                  const int* __restrict__ bidx,
                                                  const float* __restrict__ btab,
                                                  int n_off, u16* __restrict__ bm,
                                                  const float* ln1g, const float* ln1b,
                                                  const float* ln2g, const float* ln2b,
                                                  const float* bqkv, const float* b1,
                                                  float* bqf, float* b1f) {
    __shared__ float s[16][17];
    __shared__ float rb[4][64];
    int f = blockIdx.x;
    if (f >= 3328) {                       // bias fold: b + beta @ W
        int f2 = f - 3328;
        const float* W; const float* beta; const float* bb; float* outb; int N, n0;
        if (f2 < 9) { W = w0; beta = ln1b; bb = bqkv; outb = bqf; N = 576; n0 = f2 * 64; }
        else        { W = w2; beta = ln2b; bb = b1;   outb = b1f; N = 768; n0 = (f2 - 9) * 64; }
        int col = threadIdx.x & 63, seg = threadIdx.x >> 6;
        float p = 0.f;
        for (int k = seg * 48; k < seg * 48 + 48; ++k)
            p += beta[k] * W[(size_t)k * N + n0 + col];
        rb[seg][col] = p;
        __syncthreads();
        if (seg == 0)
            outb[n0 + col] = bb[n0 + col] + rb[0][col] + rb[1][col] + rb[2][col] + rb[3][col];
        return;
    }
    if (f >= 1728) {                       // bias matrix
        size_t flat = (size_t)(f - 1728) * 1024 + (size_t)threadIdx.x * 4;
        int4 iv = *(const int4*)(bidx + flat);
        #pragma unroll
        for (int h = 0; h < HEADS; ++h) {
            const float* tab = btab + (size_t)h * n_off;
            ushort4 o;
            o.x = f2bf(tab[iv.x] * L2E);
            o.y = f2bf(tab[iv.y] * L2E);
            o.z = f2bf(tab[iv.z] * L2E);
            o.w = f2bf(tab[iv.w] * L2E);
            *(ushort4*)(bm + (size_t)h * (LTOK * LTOK) + flat) = o;
        }
        return;
    }
    const float* in; u16* out; const float* gam; int K, N, tn, tk;
    if (f < 432)       { in = w0; out = o0; gam = ln1g; K = 192; N = 576; int r = f;        tn = r % 36; tk = r / 36; }
    else if (f < 576)  { in = w1; out = o1; gam = nullptr; K = 192; N = 192; int r = f - 432;  tn = r % 12; tk = r / 12; }
    else if (f < 1152) { in = w2; out = o2; gam = ln2g; K = 192; N = 768; int r = f - 576;  tn = r % 48; tk = r / 48; }
    else               { in = w3; out = o3; gam = nullptr; K = 768; N = 192; int r = f - 1152; tn = r % 12; tk = r / 12; }
    int tx = threadIdx.x & 15, ty = threadIdx.x >> 4;
    s[ty][tx] = in[(size_t)(tk * 16 + ty) * N + tn * 16 + tx];
    __syncthreads();
    float gs = gam ? gam[tk * 16 + tx] : 1.0f;
    out[(size_t)(tn * 16 + ty) * K + tk * 16 + tx] = f2bf(s[tx][ty] * gs);
}

// ---------------- MFMA GEMM: C = act(A@W + bias) (+R)  --------------------
// A bf16 [M][K] row-major, Wt bf16 [N][K]. 256 thr = 4 waves.
template<int ACT, int RES, int OBF, int K, int MTILE>
__global__ __launch_bounds__(256) void gemm_mfma(const u16* __restrict__ A,
                                                 const u16* __restrict__ Wt,
                                                 const float* __restrict__ bias,
                                                 const float* __restrict__ R,
                                                 void* __restrict__ Cp,
                                                 int N) {
    constexpr int SUB = MTILE / 64;
    int tid = threadIdx.x;
    int L = tid & 63, w = tid >> 6;
    int r = L & 15, g = L >> 4;
    int m0 = blockIdx.y * MTILE + w * (16 * SUB);
    int n0 = blockIdx.x * 64;

    f32x4 acc[SUB][4] = {};
    const u16* Ab = A + (size_t)(m0 + r) * K + g * 8;
    const u16* Wb = Wt + (size_t)(n0 + r) * K + g * 8;
    #pragma unroll 6
    for (int k0 = 0; k0 < K; k0 += 32) {
        s16x8 af[SUB];
        #pragma unroll
        for (int mi = 0; mi < SUB; ++mi)
            af[mi] = *(const s16x8*)(Ab + (size_t)mi * 16 * K + k0);
        #pragma unroll
        for (int nn = 0; nn < 4; ++nn) {
            s16x8 bf = *(const s16x8*)(Wb + (size_t)nn * 16 * K + k0);
            #pragma unroll
            for (int mi = 0; mi < SUB; ++mi)
                acc[mi][nn] = __builtin_amdgcn_mfma_f32_16x16x32_bf16(af[mi], bf, acc[mi][nn], 0, 0, 0);
        }
    }

    #pragma unroll
    for (int mi = 0; mi < SUB; ++mi)
    #pragma unroll
    for (int nn = 0; nn < 4; ++nn) {
        int cb = n0 + nn * 16;
        #pragma unroll
        for (int i = 0; i < 4; ++i) {
            int row = m0 + mi * 16 + g * 4 + i;
            float v = acc[mi][nn][i] + bias[cb + r];
            if (ACT == 1) {
                float u = v;
                float y = 0.7978845608028654f * (u + 0.044715f * u * u * u);
                float e2 = fexp2(y * 2.885390081777927f);
                v = u - u * frcp(e2 + 1.0f);
            }
            if (RES) v += R[(size_t)row * N + cb + r];
            if (OBF) ((u16*)Cp)[(size_t)row * N + cb + r] = f2bf(v);
            else     ((float*)Cp)[(size_t)row * N + cb + r] = v;
        }
    }
}

// ------ LN-fused MFMA GEMM: C = act(LNrow(A) @ (gamma-folded Wt) + biasf) --
// A f32 [M][192]; per-row (x-mu)*inv computed in-register (4-lane butterfly).
// QKV=1: scatter q (scaled)/K/V into attention layouts. ACT=1: GELU -> bf16.
template<int ACT, int QKV>
__global__ __launch_bounds__(256) void gemm_ln_mfma(const float* __restrict__ A,
                                                    const u16* __restrict__ Wt,
                                                    const float* __restrict__ biasf,
                                                    void* __restrict__ Cp,
                                                    u16* __restrict__ qb,
                                                    u16* __restrict__ kp,
                                                    u16* __restrict__ vp,
                                                    int N) {
    constexpr int K = 192;
    int tid = threadIdx.x;
    int L = tid & 63, w = tid >> 6;
    int r = L & 15, g = L >> 4;
    int m0 = blockIdx.y * 64 + w * 16;
    int n0 = blockIdx.x * 64;

    const float* Ar = A + (size_t)(m0 + r) * K;
    float4 xv[12];
    #pragma unroll
    for (int kk = 0; kk < 6; ++kk) {
        xv[2 * kk]     = *(const float4*)(Ar + kk * 32 + g * 8);
        xv[2 * kk + 1] = *(const float4*)(Ar + kk * 32 + g * 8 + 4);
    }
    float s = 0.f, ss = 0.f;
    #pragma unroll
    for (int i = 0; i < 12; ++i) {
        s  += xv[i].x + xv[i].y + xv[i].z + xv[i].w;
        ss += xv[i].x * xv[i].x + xv[i].y * xv[i].y + xv[i].z * xv[i].z + xv[i].w * xv[i].w;
    }
    s  += __shfl_xor(s, 16);  s  += __shfl_xor(s, 32);
    ss += __shfl_xor(ss, 16); ss += __shfl_xor(ss, 32);
    float mu  = s * (1.0f / K);
    float var = ss * (1.0f / K) - mu * mu;
    float inv = rsqrtf(var + 1e-5f);

    s16x8 af[6];
    #pragma unroll
    for (int kk = 0; kk < 6; ++kk) {
        float vs[8] = {xv[2*kk].x, xv[2*kk].y, xv[2*kk].z, xv[2*kk].w,
                       xv[2*kk+1].x, xv[2*kk+1].y, xv[2*kk+1].z, xv[2*kk+1].w};
        #pragma unroll
        for (int j = 0; j < 8; ++j) af[kk][j] = (short)f2bf((vs[j] - mu) * inv);
    }

    f32x4 acc[4] = {};
    const u16* Wb = Wt + (size_t)(n0 + r) * K + g * 8;
    #pragma unroll
    for (int kk = 0; kk < 6; ++kk) {
        #pragma unroll
        for (int nn = 0; nn < 4; ++nn) {
            s16x8 bf = *(const s16x8*)(Wb + (size_t)nn * 16 * K + kk * 32);
            acc[nn] = __builtin_amdgcn_mfma_f32_16x16x32_bf16(af[kk], bf, acc[nn], 0, 0, 0);
        }
    }

    #pragma unroll
    for (int nn = 0; nn < 4; ++nn) {
        int cb = n0 + nn * 16;
        #pragma unroll
        for (int i = 0; i < 4; ++i) {
            int row = m0 + g * 4 + i;
            float v = acc[nn][i] + biasf[cb + r];
            if (QKV) {
                int h  = cb / 96, c0 = cb % 96;
                int reg = c0 >> 5;               // 0=q, 1=k, 2=v
                if (reg == 0) {
                    v *= QS;
                    qb[(size_t)row * DIMC + h * 32 + (c0 & 31) + r] = f2bf(v);
                } else {
                    int b_ = row / LTOK, t = row - b_ * LTOK;
                    int T = t >> 5, it = t & 31;
                    int d = (c0 & 31) + r;
                    if (reg == 1) {
                        int which = (it >> 2) & 1;
                        int ik = ((it >> 3) << 2) | (it & 3);
                        int Lk = ((d >> 3) << 4) + ik;
                        kp[((size_t)(b_ * HEADS + h) * 40 + T) * 1024 + which * 512 + Lk * 8 + (d & 7)] = f2bf(v);
                    } else {
                        int Lv = ((it >> 3) << 4) + (d & 15);
                        vp[((size_t)(b_ * HEADS + h) * 40 + T) * 1024 + (d >> 4) * 512 + Lv * 8 + (it & 7)] = f2bf(v);
                    }
                }
            } else {
                if (ACT == 1) {
                    float u = v;
                    float y = 0.7978845608028654f * (u + 0.044715f * u * u * u);
                    float e2 = fexp2(y * 2.885390081777927f);
                    v = u - u * frcp(e2 + 1.0f);
                }
                ((u16*)Cp)[(size_t)row * N + cb + r] = f2bf(v);
            }
        }
    }
}

// ---- MFMA flash attention: LDS-shared K/V per (b,h,64q), dbuf pipeline ----
// 960 blocks = (b 8) x (h 6) x (qg 20), XCD-chunk swizzled so the 8 batches
// of one (h,qg) share an XCD (bm L2-local). 4 waves/block, wave w owns
// q-rows [qg*64 + w*16, +16). Per 32-key tile the block stages K+V (4KB)
// into double-buffered LDS (16B/thread, write-late), 1 barrier/iter.
__global__ __launch_bounds__(256) void attn_mfma(const u16* __restrict__ qb,
                                                 const u16* __restrict__ kp,
                                                 const u16* __restrict__ vp,
                                                 const u16* __restrict__ bm,
                                                 u16* __restrict__ ob) {
    __shared__ __align__(16) u16 kvs[2][2][1024];   // [dbuf][k/v] 8KB
    int tid = threadIdx.x;
    int L = tid & 63, w = tid >> 6;
    int r = L & 15, g = L >> 4;
    int L8 = L * 8;

    int bid = blockIdx.x;
    int work = (bid & 7) * 120 + (bid >> 3);     // 960 = 8 * 120
    int b  = work & 7;
    int hq = work >> 3;                          // 0..119
    int qt = (hq % 20) * 4 + w;                  // 16-row q-tile, 0..79
    int h  = hq / 20;

    s16x8 qf = *(const s16x8*)(qb + (size_t)(b * LTOK + qt * 16 + r) * DIMC + h * 32 + g * 8);

    // stage assignment: wave -> (k/v, half), 16B per thread per tile
    int skv = w >> 1, half = w & 1;
    const u16* gsrc = (skv ? vp : kp) + (size_t)(b * HEADS + h) * 40 * 1024 + half * 512 + L8;
    u16* d0 = &kvs[0][skv][half * 512 + L8];
    u16* d1 = &kvs[1][skv][half * 512 + L8];

    const u16* bmr = bm + ((size_t)h * LTOK + qt * 16 + r) * LTOK + g * 8;

    f32x4 acc0 = {0.f, 0.f, 0.f, 0.f}, acc1 = {0.f, 0.f, 0.f, 0.f};
    float lsum = 0.f;

    int4 sA = *(const int4*)(gsrc);
    int4 bvn = *(const int4*)(bmr);
    *(int4*)d0 = sA;
    __syncthreads();

    #pragma unroll 1
    for (int T = 0; T < 40; ++T) {
        int buf = T & 1;
        if (T < 39) sA = *(const int4*)(gsrc + (size_t)(T + 1) * 1024);
        int4 bv = bvn;
        if (T < 39) bvn = *(const int4*)(bmr + (size_t)(T + 1) * 32);

        f32x4 z0, z1;
        z0[0] = bflo(bv.x); z0[1] = bfhi(bv.x); z0[2] = bflo(bv.y); z0[3] = bfhi(bv.y);
        z1[0] = bflo(bv.z); z1[1] = bfhi(bv.z); z1[2] = bflo(bv.w); z1[3] = bfhi(bv.w);

        s16x8 kf0 = *(const s16x8*)&kvs[buf][0][L8];
        s16x8 kf1 = *(const s16x8*)&kvs[buf][0][512 + L8];
        f32x4 s0 = __builtin_amdgcn_mfma_f32_16x16x32_bf16(kf0, qf, z0, 0, 0, 0);
        f32x4 s1 = __builtin_amdgcn_mfma_f32_16x16x32_bf16(kf1, qf, z1, 0, 0, 0);
        float p[8];
        #pragma unroll
        for (int j = 0; j < 4; ++j) p[j] = fexp2(s0[j]);
        #pragma unroll
        for (int j = 0; j < 4; ++j) p[4 + j] = fexp2(s1[j]);
        lsum += ((p[0] + p[1]) + (p[2] + p[3])) + ((p[4] + p[5]) + (p[6] + p[7]));
        union { unsigned u[4]; s16x8 v; } pbu;
        #pragma unroll
        for (int j = 0; j < 4; ++j)
            asm("v_cvt_pk_bf16_f32 %0, %1, %2" : "=v"(pbu.u[j]) : "v"(p[2 * j]), "v"(p[2 * j + 1]));
        s16x8 v0 = *(const s16x8*)&kvs[buf][1][L8];
        s16x8 v1 = *(const s16x8*)&kvs[buf][1][512 + L8];
        acc0 = __builtin_amdgcn_mfma_f32_16x16x32_bf16(pbu.v, v0, acc0, 0, 0, 0);
        acc1 = __builtin_amdgcn_mfma_f32_16x16x32_bf16(pbu.v, v1, acc1, 0, 0, 0);

        if (T < 39) *(int4*)((T & 1) ? d0 : d1) = sA;
        __syncthreads();
    }

    float lr = lsum;
    lr += __shfl_xor(lr, 16);
    lr += __shfl_xor(lr, 32);
    #pragma unroll
    for (int i = 0; i < 4; ++i) {
        float linv = frcp(__shfl(lr, 4 * g + i));
        size_t orow = (size_t)(b * LTOK + qt * 16 + 4 * g + i) * DIMC + h * 32 + r;
        ob[orow]      = f2bf(acc0[i] * linv);
        ob[orow + 16] = f2bf(acc1[i] * linv);
    }
}

// ---------------- Depthwise 3x3 conv + BN, float4 channels -----------------
__global__ __launch_bounds__(256) void conv_bn_kernel(const float* __restrict__ xm,
                                                      const float* __restrict__ w,
                                                      const float* __restrict__ scale,
                                                      const float* __restrict__ bias,
                                                      float* __restrict__ out) {
    int idx = blockIdx.x * 256 + threadIdx.x;   // NROWS*48
    int cc = idx % 48, p = idx / 48;
    int c = cc * 4;
    int b = p / LTOK, t = p - b * LTOK;
    int H, W, base, y, x;
    if (t < 1024) { H = 32; W = 32; base = 0;    y = t >> 5;            x = t & 31; }
    else          { H = 16; W = 16; base = 1024; int tt = t - 1024; y = tt >> 4; x = tt & 15; }
    float4 acc = {0.f, 0.f, 0.f, 0.f};
    #pragma unroll
    for (int ky = 0; ky < 3; ++ky) {
        int yy = y + ky - 1;
        if (yy < 0 || yy >= H) continue;
        #pragma unroll
        for (int kx = 0; kx < 3; ++kx) {
            int xx = x + kx - 1;
            if (xx < 0 || xx >= W) continue;
            float4 wv = *(const float4*)(w + (ky * 3 + kx) * DIMC + c);
            float4 xv = *(const float4*)(xm + (size_t)(b * LTOK + base + yy * W + xx) * DIMC + c);
            acc.x += wv.x * xv.x; acc.y += wv.y * xv.y;
            acc.z += wv.z * xv.z; acc.w += wv.w * xv.w;
        }
    }
    float4 sv = *(const float4*)(scale + c);
    float4 bv = *(const float4*)(bias + c);
    float4 o;
    o.x = acc.x * sv.x + bv.x; o.y = acc.y * sv.y + bv.y;
    o.z = acc.z * sv.z + bv.z; o.w = acc.w * sv.w + bv.w;
    *(float4*)(out + (size_t)(b * LTOK + t) * DIMC + c) = o;
}

// ---------------------------------------------------------------------------
extern "C" void kernel_launch(void* const* d_in, const int* in_sizes, int n_in,
                              void* d_out, int out_size, void* d_ws, size_t ws_size,
                              hipStream_t stream) {
    const float* xz       = (const float*)d_in[0];
    const int*   bidx     = (const int*)  d_in[1];
    const float* ln1_g    = (const float*)d_in[2];
    const float* ln1_b    = (const float*)d_in[3];
    const float* wqkv     = (const float*)d_in[4];
    const float* bqkv     = (const float*)d_in[5];
    const float* wproj    = (const float*)d_in[6];
    const float* bproj    = (const float*)d_in[7];
    const float* btab     = (const float*)d_in[8];
    const float* conv_w   = (const float*)d_in[9];
    const float* bn_scale = (const float*)d_in[10];
    const float* bn_bias  = (const float*)d_in[11];
    const float* ln2_g    = (const float*)d_in[12];
    const float* ln2_b    = (const float*)d_in[13];
    const float* w1       = (const float*)d_in[14];
    const float* b1       = (const float*)d_in[15];
    const float* w2       = (const float*)d_in[16];
    const float* b2       = (const float*)d_in[17];
    int n_off = in_sizes[8] / HEADS;
    float* out = (float*)d_out;

    // ---- workspace layout (bytes), liveness overlays; peak 40.2 MB ----
    char* wsb = (char*)d_ws;
    u16*  ob     = (u16*)(wsb + 0);                    // attn out (3.9MB)
    u16*  wqkvT  = (u16*)(wsb + 3932160);
    u16*  wprojT = (u16*)(wsb + 4153344);
    u16*  w1T    = (u16*)(wsb + 4227072);
    u16*  w2T    = (u16*)(wsb + 4521984);
    u16*  bm     = (u16*)(wsb + 4816896);              // 19.6MB; hid overlays
    u16*  hid    = (u16*)(wsb + 4816896);
    u16*  kp     = (u16*)(wsb + 24477696);
    u16*  vp     = (u16*)(wsb + 28409856);
    float* xm2   = (float*)(wsb + 24477696);           // overlays kp/vp (post-attn)
    u16*  qb     = (u16*)(wsb + 32342016);
    float* xm    = (float*)(wsb + 32342016);           // overlays qb (post-attn)
    // folded biases live in d_out scratch (overwritten by fc2 at the end)
    float* bqf = (float*)d_out;            // 576 f32
    float* b1f = (float*)d_out + 576;      // 768 f32

    // 1) preprocess: gamma-folded weight transposes, bias folds, bias matrix
    pre_kernel<<<3349, 256, 0, stream>>>(
        wqkv, wproj, w1, w2, wqkvT, wprojT, w1T, w2T, bidx, btab, n_off, bm,
        ln1_g, ln1_b, ln2_g, ln2_b, bqkv, b1, bqf, b1f);
    // 2) LN1-fused QKV GEMM from xz, scattering q/K/V into attention layouts
    gemm_ln_mfma<0,1><<<dim3(9, 160), 256, 0, stream>>>(
        xz, wqkvT, bqf, nullptr, qb, kp, vp, 3 * DIMC);
    // 3) attention (LDS-shared KV, XCD-swizzled, 960 blocks)
    attn_mfma<<<960, 256, 0, stream>>>(qb, kp, vp, bm, ob);
    // 4) proj + residual(xz) -> xm f32
    gemm_mfma<0,1,0,DIMC,64><<<dim3(3, 160), 256, 0, stream>>>(
        ob, wprojT, bproj, xz, xm, DIMC);
    // 5) depthwise conv + BN -> xm2 f32
    conv_bn_kernel<<<NROWS * 48 / 256, 256, 0, stream>>>(xm, conv_w, bn_scale, bn_bias, xm2);
    // 6) LN2-fused fc1 + GELU from xm2 -> hid bf16
    gemm_ln_mfma<1,0><<<dim3(12, 160), 256, 0, stream>>>(
        xm2, w1T, b1f, hid, nullptr, nullptr, nullptr, HID);
    // 7) fc2 + residual(xm2) -> out f32
    gemm_mfma<0,1,0,HID,128><<<dim3(3, 80), 256, 0, stream>>>(
        hid, w2T, b2, xm2, out, DIMC);
}

// Round 8
// 136.032 us; speedup vs baseline: 1.1413x; 1.1413x over previous
//
#include <hip/hip_runtime.h>
#include <hip/hip_bf16.h>

#define BATCH 8
#define LTOK 1280
#define DIMC 192
#define HEADS 6
#define KD 32
#define HID 768
#define NROWS (BATCH*LTOK)   // 10240

typedef short s16x8 __attribute__((ext_vector_type(8)));
typedef float f32x4 __attribute__((ext_vector_type(4)));
typedef unsigned short u16;

// q pre-scale: 32^-0.5 * log2(e)  (softmax runs in exp2 domain)
#define QS (0.17677669529663687f * 1.4426950408889634f)
#define L2E 1.4426950408889634f

__device__ __forceinline__ u16 f2bf(float x) {
    unsigned u = __float_as_uint(x);
    u = (u + 0x7FFFu + ((u >> 16) & 1u)) >> 16;
    return (u16)u;
}
__device__ __forceinline__ float bflo(unsigned u) { return __uint_as_float(u << 16); }
__device__ __forceinline__ float bfhi(unsigned u) { return __uint_as_float(u & 0xffff0000u); }
__device__ __forceinline__ float fexp2(float x) { float r; asm("v_exp_f32 %0, %1" : "=v"(r) : "v"(x)); return r; }
__device__ __forceinline__ float frcp(float x)  { float r; asm("v_rcp_f32 %0, %1" : "=v"(r) : "v"(x)); return r; }

// ---------------- LayerNorm -> bf16: 4 rows/block, 64 lanes per row --------
__global__ __launch_bounds__(256) void ln_kernel(const float* __restrict__ x,
                                                 const float* __restrict__ g,
                                                 const float* __restrict__ b,
                                                 u16* __restrict__ y) {
    int row = blockIdx.x * 4 + (threadIdx.x >> 6);
    int lane = threadIdx.x & 63;
    const float* xr = x + (size_t)row * DIMC;
    float v0 = xr[lane], v1 = xr[lane + 64], v2 = xr[lane + 128];
    float s = v0 + v1 + v2;
    float ss = v0 * v0 + v1 * v1 + v2 * v2;
    #pragma unroll
    for (int off = 32; off; off >>= 1) {
        s  += __shfl_xor(s, off);
        ss += __shfl_xor(ss, off);
    }
    float mu  = s * (1.0f / DIMC);
    float var = ss * (1.0f / DIMC) - mu * mu;
    float inv = rsqrtf(var + 1e-5f);
    u16* yr = y + (size_t)row * DIMC;
    yr[lane]       = f2bf((v0 - mu) * inv * g[lane]       + b[lane]);
    yr[lane + 64]  = f2bf((v1 - mu) * inv * g[lane + 64]  + b[lane + 64]);
    yr[lane + 128] = f2bf((v2 - mu) * inv * g[lane + 128] + b[lane + 128]);
}

// ------- Preprocess (merged): weight transpose/convert + bias matrix -------
// blocks [0,1728): W[K][N] f32 -> Wt[N][K] bf16 ; blocks [1728, 3328): bm
__global__ __launch_bounds__(256) void pre_kernel(const float* w0, const float* w1,
                                                  const float* w2, const float* w3,
                                                  u16* o0, u16* o1, u16* o2, u16* o3,
                                                  const int* __restrict__ bidx,
                                                  const float* __restrict__ btab,
                                                  int n_off, u16* __restrict__ bm) {
    __shared__ float s[16][17];
    int f = blockIdx.x;
    if (f >= 1728) {
        size_t flat = (size_t)(f - 1728) * 1024 + (size_t)threadIdx.x * 4;
        int4 iv = *(const int4*)(bidx + flat);
        #pragma unroll
        for (int h = 0; h < HEADS; ++h) {
            const float* tab = btab + (size_t)h * n_off;
            ushort4 o;
            o.x = f2bf(tab[iv.x] * L2E);
            o.y = f2bf(tab[iv.y] * L2E);
            o.z = f2bf(tab[iv.z] * L2E);
            o.w = f2bf(tab[iv.w] * L2E);
            *(ushort4*)(bm + (size_t)h * (LTOK * LTOK) + flat) = o;
        }
        return;
    }
    const float* in; u16* out; int K, N, tn, tk;
    if (f < 432)       { in = w0; out = o0; K = 192; N = 576; int r = f;        tn = r % 36; tk = r / 36; }
    else if (f < 576)  { in = w1; out = o1; K = 192; N = 192; int r = f - 432;  tn = r % 12; tk = r / 12; }
    else if (f < 1152) { in = w2; out = o2; K = 192; N = 768; int r = f - 576;  tn = r % 48; tk = r / 48; }
    else               { in = w3; out = o3; K = 768; N = 192; int r = f - 1152; tn = r % 12; tk = r / 12; }
    int tx = threadIdx.x & 15, ty = threadIdx.x >> 4;
    s[ty][tx] = in[(size_t)(tk * 16 + ty) * N + tn * 16 + tx];
    __syncthreads();
    out[(size_t)(tn * 16 + ty) * K + tk * 16 + tx] = f2bf(s[tx][ty]);
}

// ---------------- MFMA GEMM: C = act(A@W + bias) (+R)  --------------------
// A bf16 [M][K] row-major, Wt bf16 [N][K]. 256 thr = 4 waves.
// MTILE=128: wave tile 32x64; MTILE=64: wave tile 16x64. K compile-time.
template<int ACT, int RES, int OBF, int QKV, int K, int MTILE>
__global__ __launch_bounds__(256) void gemm_mfma(const u16* __restrict__ A,
                                                 const u16* __restrict__ Wt,
                                                 const float* __restrict__ bias,
                                                 const float* __restrict__ R,
                                                 void* __restrict__ Cp,
                                                 u16* __restrict__ qb,
                                                 u16* __restrict__ kp,
                                                 u16* __restrict__ vp,
                                                 int N) {
    constexpr int SUB = MTILE / 64;          // fragments per wave in M
    int tid = threadIdx.x;
    int L = tid & 63, w = tid >> 6;
    int r = L & 15, g = L >> 4;
    int m0 = blockIdx.y * MTILE + w * (16 * SUB);
    int n0 = blockIdx.x * 64;

    f32x4 acc[SUB][4] = {};
    const u16* Ab = A + (size_t)(m0 + r) * K + g * 8;
    const u16* Wb = Wt + (size_t)(n0 + r) * K + g * 8;
    #pragma unroll 6
    for (int k0 = 0; k0 < K; k0 += 32) {
        s16x8 af[SUB];
        #pragma unroll
        for (int mi = 0; mi < SUB; ++mi)
            af[mi] = *(const s16x8*)(Ab + (size_t)mi * 16 * K + k0);
        #pragma unroll
        for (int nn = 0; nn < 4; ++nn) {
            s16x8 bf = *(const s16x8*)(Wb + (size_t)nn * 16 * K + k0);
            #pragma unroll
            for (int mi = 0; mi < SUB; ++mi)
                acc[mi][nn] = __builtin_amdgcn_mfma_f32_16x16x32_bf16(af[mi], bf, acc[mi][nn], 0, 0, 0);
        }
    }

    #pragma unroll
    for (int mi = 0; mi < SUB; ++mi)
    #pragma unroll
    for (int nn = 0; nn < 4; ++nn) {
        int cb = n0 + nn * 16;
        #pragma unroll
        for (int i = 0; i < 4; ++i) {
            int row = m0 + mi * 16 + g * 4 + i;
            float v = acc[mi][nn][i] + bias[cb + r];
            if (QKV) {
                int h  = cb / 96, c0 = cb % 96;
                int reg = c0 >> 5;               // 0=q, 1=k, 2=v
                if (reg == 0) {
                    v *= QS;
                    qb[(size_t)row * DIMC + h * 32 + (c0 & 31) + r] = f2bf(v);
                } else {
                    int b_ = row / LTOK, t = row - b_ * LTOK;
                    int T = t >> 5, it = t & 31;
                    int d = (c0 & 31) + r;
                    if (reg == 1) {
                        int which = (it >> 2) & 1;
                        int ik = ((it >> 3) << 2) | (it & 3);
                        int Lk = ((d >> 3) << 4) + ik;
                        kp[((size_t)(b_ * HEADS + h) * 40 + T) * 1024 + which * 512 + Lk * 8 + (d & 7)] = f2bf(v);
                    } else {
                        int Lv = ((it >> 3) << 4) + (d & 15);
                        vp[((size_t)(b_ * HEADS + h) * 40 + T) * 1024 + (d >> 4) * 512 + Lv * 8 + (it & 7)] = f2bf(v);
                    }
                }
            } else {
                if (ACT == 1) {
                    float u = v;
                    float y = 0.7978845608028654f * (u + 0.044715f * u * u * u);
                    float e2 = fexp2(y * 2.885390081777927f);   // 2*log2(e)
                    v = u - u * frcp(e2 + 1.0f);                // 0.5u(1+tanh(y))
                }
                if (RES) v += R[(size_t)row * N + cb + r];
                if (OBF) ((u16*)Cp)[(size_t)row * N + cb + r] = f2bf(v);
                else     ((float*)Cp)[(size_t)row * N + cb + r] = v;
            }
        }
    }
}

// ---- MFMA flash attention: LDS K/V, tri-buffer depth-2 prefetch -----------
// 960 blocks = (b 8) x (h 6) x (qg 20), XCD-chunk swizzled (batch innermost
// so the 8 batches of one (h,qg) share an XCD: bm L2-local). 4 waves/block,
// wave w owns q-rows [qg*64+w*16, +16). Global load for tile T+2 issues at
// iter T; ds_write of tile T+1 at end of iter T; 1 barrier/iter.
__global__ __launch_bounds__(256) void attn_mfma(const u16* __restrict__ qb,
                                                 const u16* __restrict__ kp,
                                                 const u16* __restrict__ vp,
                                                 const u16* __restrict__ bm,
                                                 u16* __restrict__ ob) {
    __shared__ __align__(16) u16 kvs[3][2][1024];   // [tri-buf][k/v] 12KB
    int tid = threadIdx.x;
    int L = tid & 63, w = tid >> 6;
    int r = L & 15, g = L >> 4;
    int L8 = L * 8;

    int bid = blockIdx.x;
    int work = (bid & 7) * 120 + (bid >> 3);     // 960 = 8 * 120
    int b  = work & 7;
    int hq = work >> 3;                          // 0..119
    int qt = (hq % 20) * 4 + w;                  // 16-row q-tile, 0..79
    int h  = hq / 20;

    s16x8 qf = *(const s16x8*)(qb + (size_t)(b * LTOK + qt * 16 + r) * DIMC + h * 32 + g * 8);

    // stage assignment: wave -> (k/v, half), 16B per thread per tile
    int skv = w >> 1, half = w & 1;
    const u16* gsrc = (skv ? vp : kp) + (size_t)(b * HEADS + h) * 40 * 1024 + half * 512 + L8;
    u16* kvsb = &kvs[0][0][0];
    int dofs = skv * 1024 + half * 512 + L8;     // offset within one buffer

    const u16* bmr = bm + ((size_t)h * LTOK + qt * 16 + r) * LTOK + g * 8;

    f32x4 acc0 = {0.f, 0.f, 0.f, 0.f}, acc1 = {0.f, 0.f, 0.f, 0.f};
    float lsum = 0.f;

    // prologue: tile0 -> buf0 (stalls once), tile1 held in regs, bias 0/1
    int4 st0 = *(const int4*)(gsrc);
    *(int4*)(kvsb + dofs) = st0;
    int4 sCur = *(const int4*)(gsrc + 1024);
    int4 bv  = *(const int4*)(bmr);
    int4 bvn = *(const int4*)(bmr + 32);
    __syncthreads();

    int rd = 0, wr = 1;
    #pragma unroll 1
    for (int T = 0; T < 40; ++T) {
        int4 sNext, bb;
        if (T < 38) {
            sNext = *(const int4*)(gsrc + (size_t)(T + 2) * 1024);
            bb    = *(const int4*)(bmr + (size_t)(T + 2) * 32);
        }
        u16* bufr = kvsb + rd * 2048;
        f32x4 z0, z1;
        z0[0] = bflo(bv.x); z0[1] = bfhi(bv.x); z0[2] = bflo(bv.y); z0[3] = bfhi(bv.y);
        z1[0] = bflo(bv.z); z1[1] = bfhi(bv.z); z1[2] = bflo(bv.w); z1[3] = bfhi(bv.w);

        s16x8 kf0 = *(const s16x8*)(bufr + L8);
        s16x8 kf1 = *(const s16x8*)(bufr + 512 + L8);
        __builtin_amdgcn_s_setprio(1);
        f32x4 s0 = __builtin_amdgcn_mfma_f32_16x16x32_bf16(kf0, qf, z0, 0, 0, 0);
        f32x4 s1 = __builtin_amdgcn_mfma_f32_16x16x32_bf16(kf1, qf, z1, 0, 0, 0);
        float p[8];
        #pragma unroll
        for (int j = 0; j < 4; ++j) p[j] = fexp2(s0[j]);
        #pragma unroll
        for (int j = 0; j < 4; ++j) p[4 + j] = fexp2(s1[j]);
        lsum += ((p[0] + p[1]) + (p[2] + p[3])) + ((p[4] + p[5]) + (p[6] + p[7]));
        union { unsigned u[4]; s16x8 v; } pbu;
        #pragma unroll
        for (int j = 0; j < 4; ++j)
            asm("v_cvt_pk_bf16_f32 %0, %1, %2" : "=v"(pbu.u[j]) : "v"(p[2 * j]), "v"(p[2 * j + 1]));
        s16x8 v0 = *(const s16x8*)(bufr + 1024 + L8);
        s16x8 v1 = *(const s16x8*)(bufr + 1536 + L8);
        acc0 = __builtin_amdgcn_mfma_f32_16x16x32_bf16(pbu.v, v0, acc0, 0, 0, 0);
        acc1 = __builtin_amdgcn_mfma_f32_16x16x32_bf16(pbu.v, v1, acc1, 0, 0, 0);
        __builtin_amdgcn_s_setprio(0);

        if (T < 39) *(int4*)(kvsb + wr * 2048 + dofs) = sCur;
        __syncthreads();
        sCur = sNext; bv = bvn; bvn = bb;
        rd = wr; wr = (wr == 2) ? 0 : wr + 1;
    }

    float lr = lsum;
    lr += __shfl_xor(lr, 16);
    lr += __shfl_xor(lr, 32);
    #pragma unroll
    for (int i = 0; i < 4; ++i) {
        float linv = frcp(__shfl(lr, 4 * g + i));
        size_t orow = (size_t)(b * LTOK + qt * 16 + 4 * g + i) * DIMC + h * 32 + r;
        ob[orow]      = f2bf(acc0[i] * linv);
        ob[orow + 16] = f2bf(acc1[i] * linv);
    }
}

// ------- Depthwise 3x3 conv + BN + LayerNorm2 fused (wave per row) ---------
// Writes xm2 (f32, fc2 residual) and hbuf (bf16 LN2 output, fc1 input).
__global__ __launch_bounds__(256) void conv_ln_kernel(const float* __restrict__ xm,
                                                      const float* __restrict__ w,
                                                      const float* __restrict__ scale,
                                                      const float* __restrict__ bias,
                                                      const float* __restrict__ g2,
                                                      const float* __restrict__ b2,
                                                      float* __restrict__ xm2,
                                                      u16* __restrict__ y) {
    int row = blockIdx.x * 4 + (threadIdx.x >> 6);
    int lane = threadIdx.x & 63;
    int b = row / LTOK, t = row - b * LTOK;
    int H, W, base, y0, x0;
    if (t < 1024) { H = 32; W = 32; base = 0;    y0 = t >> 5;            x0 = t & 31; }
    else          { H = 16; W = 16; base = 1024; int tt = t - 1024; y0 = tt >> 4; x0 = tt & 15; }
    float a0 = 0.f, a1 = 0.f, a2 = 0.f;
    #pragma unroll
    for (int ky = 0; ky < 3; ++ky) {
        int yy = y0 + ky - 1;
        if (yy < 0 || yy >= H) continue;
        #pragma unroll
        for (int kx = 0; kx < 3; ++kx) {
            int xx = x0 + kx - 1;
            if (xx < 0 || xx >= W) continue;
            const float* xr = xm + (size_t)(b * LTOK + base + yy * W + xx) * DIMC;
            const float* wr = w + (ky * 3 + kx) * DIMC;
            a0 += wr[lane]       * xr[lane];
            a1 += wr[lane + 64]  * xr[lane + 64];
            a2 += wr[lane + 128] * xr[lane + 128];
        }
    }
    float v0 = a0 * scale[lane]       + bias[lane];
    float v1 = a1 * scale[lane + 64]  + bias[lane + 64];
    float v2 = a2 * scale[lane + 128] + bias[lane + 128];
    float* xr2 = xm2 + (size_t)row * DIMC;
    xr2[lane] = v0; xr2[lane + 64] = v1; xr2[lane + 128] = v2;
    float s = v0 + v1 + v2;
    float ss = v0 * v0 + v1 * v1 + v2 * v2;
    #pragma unroll
    for (int off = 32; off; off >>= 1) {
        s  += __shfl_xor(s, off);
        ss += __shfl_xor(ss, off);
    }
    float mu  = s * (1.0f / DIMC);
    float var = ss * (1.0f / DIMC) - mu * mu;
    float inv = rsqrtf(var + 1e-5f);
    u16* yr = y + (size_t)row * DIMC;
    yr[lane]       = f2bf((v0 - mu) * inv * g2[lane]       + b2[lane]);
    yr[lane + 64]  = f2bf((v1 - mu) * inv * g2[lane + 64]  + b2[lane + 64]);
    yr[lane + 128] = f2bf((v2 - mu) * inv * g2[lane + 128] + b2[lane + 128]);
}

// ---------------------------------------------------------------------------
extern "C" void kernel_launch(void* const* d_in, const int* in_sizes, int n_in,
                              void* d_out, int out_size, void* d_ws, size_t ws_size,
                              hipStream_t stream) {
    const float* xz       = (const float*)d_in[0];
    const int*   bidx     = (const int*)  d_in[1];
    const float* ln1_g    = (const float*)d_in[2];
    const float* ln1_b    = (const float*)d_in[3];
    const float* wqkv     = (const float*)d_in[4];
    const float* bqkv     = (const float*)d_in[5];
    const float* wproj    = (const float*)d_in[6];
    const float* bproj    = (const float*)d_in[7];
    const float* btab     = (const float*)d_in[8];
    const float* conv_w   = (const float*)d_in[9];
    const float* bn_scale = (const float*)d_in[10];
    const float* bn_bias  = (const float*)d_in[11];
    const float* ln2_g    = (const float*)d_in[12];
    const float* ln2_b    = (const float*)d_in[13];
    const float* w1       = (const float*)d_in[14];
    const float* b1       = (const float*)d_in[15];
    const float* w2       = (const float*)d_in[16];
    const float* b2       = (const float*)d_in[17];
    int n_off = in_sizes[8] / HEADS;
    float* out = (float*)d_out;

    // ---- workspace layout (bytes), liveness overlays; peak 40.2 MB ----
    char* wsb = (char*)d_ws;
    u16*  hbuf   = (u16*)(wsb + 0);                    // ln out; ob overlays
    u16*  ob     = (u16*)(wsb + 0);
    u16*  wqkvT  = (u16*)(wsb + 3932160);
    u16*  wprojT = (u16*)(wsb + 4153344);
    u16*  w1T    = (u16*)(wsb + 4227072);
    u16*  w2T    = (u16*)(wsb + 4521984);
    u16*  bm     = (u16*)(wsb + 4816896);              // 19.6 MB; hid overlays
    u16*  hid    = (u16*)(wsb + 4816896);
    u16*  kp     = (u16*)(wsb + 24477696);
    u16*  vp     = (u16*)(wsb + 28409856);
    float* xm2   = (float*)(wsb + 24477696);           // overlays kp/vp
    u16*  qb     = (u16*)(wsb + 32342016);
    float* xm    = (float*)(wsb + 32342016);           // overlays qb

    // 1) preprocess: weight transpose/convert + bias matrix (exp2 domain)
    pre_kernel<<<1728 + LTOK * LTOK / 1024, 256, 0, stream>>>(
        wqkv, wproj, w1, w2, wqkvT, wprojT, w1T, w2T, bidx, btab, n_off, bm);
    // 2) LN1 -> bf16
    ln_kernel<<<NROWS / 4, 256, 0, stream>>>(xz, ln1_g, ln1_b, hbuf);
    // 3) QKV GEMM, scattering q/K/V into attention layouts
    gemm_mfma<0,0,0,1,DIMC,128><<<dim3(576 / 64, NROWS / 128), 256, 0, stream>>>(
        hbuf, wqkvT, bqkv, nullptr, nullptr, qb, kp, vp, 3 * DIMC);
    // 4) attention (tri-buffer LDS, depth-2 prefetch, XCD-swizzled)
    attn_mfma<<<960, 256, 0, stream>>>(qb, kp, vp, bm, ob);
    // 5) proj + residual(xz) -> xm f32
    gemm_mfma<0,1,0,0,DIMC,64><<<dim3(DIMC / 64, NROWS / 64), 256, 0, stream>>>(
        ob, wprojT, bproj, xz, xm, nullptr, nullptr, nullptr, DIMC);
    // 6) depthwise conv + BN + LN2 -> xm2 f32 + hbuf bf16
    conv_ln_kernel<<<NROWS / 4, 256, 0, stream>>>(
        xm, conv_w, bn_scale, bn_bias, ln2_g, ln2_b, xm2, hbuf);
    // 7) MLP fc1 + GELU -> hid bf16
    gemm_mfma<1,0,1,0,DIMC,128><<<dim3(HID / 64, NROWS / 128), 256, 0, stream>>>(
        hbuf, w1T, b1, nullptr, hid, nullptr, nullptr, nullptr, HID);
    // 8) MLP fc2 + residual(xm2) -> out f32
    gemm_mfma<0,1,0,0,HID,128><<<dim3(DIMC / 64, NROWS / 128), 256, 0, stream>>>(
        hid, w2T, b2, xm2, out, nullptr, nullptr, nullptr, DIMC);
}

// Round 9
// 128.851 us; speedup vs baseline: 1.2049x; 1.0557x over previous
//
#include <hip/hip_runtime.h>
#include <hip/hip_bf16.h>

#define BATCH 8
#define LTOK 1280
#define DIMC 192
#define HEADS 6
#define KD 32
#define HID 768
#define NROWS (BATCH*LTOK)   // 10240

typedef short s16x8 __attribute__((ext_vector_type(8)));
typedef float f32x4 __attribute__((ext_vector_type(4)));
typedef unsigned short u16;

// q pre-scale: 32^-0.5 * log2(e)  (softmax runs in exp2 domain)
#define QS (0.17677669529663687f * 1.4426950408889634f)
#define L2E 1.4426950408889634f

__device__ __forceinline__ u16 f2bf(float x) {
    unsigned u = __float_as_uint(x);
    u = (u + 0x7FFFu + ((u >> 16) & 1u)) >> 16;
    return (u16)u;
}
__device__ __forceinline__ float bflo(unsigned u) { return __uint_as_float(u << 16); }
__device__ __forceinline__ float bfhi(unsigned u) { return __uint_as_float(u & 0xffff0000u); }
__device__ __forceinline__ float fexp2(float x) { float r; asm("v_exp_f32 %0, %1" : "=v"(r) : "v"(x)); return r; }
__device__ __forceinline__ float frcp(float x)  { float r; asm("v_rcp_f32 %0, %1" : "=v"(r) : "v"(x)); return r; }

// --- Preprocess (merged): weight transpose/convert + bias matrix + LN1 -----
// blocks [0,1728): W[K][N] f32 -> Wt[N][K] bf16
// blocks [1728,3328): bm[h][n][m] = bf16(tab*log2e)
// blocks [3328,5888): LN1 of xz -> hbuf bf16 (4 rows/block)
__global__ __launch_bounds__(256) void pre_kernel(const float* w0, const float* w1,
                                                  const float* w2, const float* w3,
                                                  u16* o0, u16* o1, u16* o2, u16* o3,
                                                  const int* __restrict__ bidx,
                                                  const float* __restrict__ btab,
                                                  int n_off, u16* __restrict__ bm,
                                                  const float* __restrict__ xz,
                                                  const float* __restrict__ ln1g,
                                                  const float* __restrict__ ln1b,
                                                  u16* __restrict__ hbuf) {
    __shared__ float s[16][17];
    int f = blockIdx.x;
    if (f >= 3328) {                       // LN1
        int row = (f - 3328) * 4 + (threadIdx.x >> 6);
        int lane = threadIdx.x & 63;
        const float* xr = xz + (size_t)row * DIMC;
        float v0 = xr[lane], v1 = xr[lane + 64], v2 = xr[lane + 128];
        float sm = v0 + v1 + v2;
        float ss = v0 * v0 + v1 * v1 + v2 * v2;
        #pragma unroll
        for (int off = 32; off; off >>= 1) {
            sm += __shfl_xor(sm, off);
            ss += __shfl_xor(ss, off);
        }
        float mu  = sm * (1.0f / DIMC);
        float var = ss * (1.0f / DIMC) - mu * mu;
        float inv = rsqrtf(var + 1e-5f);
        u16* yr = hbuf + (size_t)row * DIMC;
        yr[lane]       = f2bf((v0 - mu) * inv * ln1g[lane]       + ln1b[lane]);
        yr[lane + 64]  = f2bf((v1 - mu) * inv * ln1g[lane + 64]  + ln1b[lane + 64]);
        yr[lane + 128] = f2bf((v2 - mu) * inv * ln1g[lane + 128] + ln1b[lane + 128]);
        return;
    }
    if (f >= 1728) {                       // bias matrix
        size_t flat = (size_t)(f - 1728) * 1024 + (size_t)threadIdx.x * 4;
        int4 iv = *(const int4*)(bidx + flat);
        #pragma unroll
        for (int h = 0; h < HEADS; ++h) {
            const float* tab = btab + (size_t)h * n_off;
            ushort4 o;
            o.x = f2bf(tab[iv.x] * L2E);
            o.y = f2bf(tab[iv.y] * L2E);
            o.z = f2bf(tab[iv.z] * L2E);
            o.w = f2bf(tab[iv.w] * L2E);
            *(ushort4*)(bm + (size_t)h * (LTOK * LTOK) + flat) = o;
        }
        return;
    }
    const float* in; u16* out; int K, N, tn, tk;
    if (f < 432)       { in = w0; out = o0; K = 192; N = 576; int r = f;        tn = r % 36; tk = r / 36; }
    else if (f < 576)  { in = w1; out = o1; K = 192; N = 192; int r = f - 432;  tn = r % 12; tk = r / 12; }
    else if (f < 1152) { in = w2; out = o2; K = 192; N = 768; int r = f - 576;  tn = r % 48; tk = r / 48; }
    else               { in = w3; out = o3; K = 768; N = 192; int r = f - 1152; tn = r % 12; tk = r / 12; }
    int tx = threadIdx.x & 15, ty = threadIdx.x >> 4;
    s[ty][tx] = in[(size_t)(tk * 16 + ty) * N + tn * 16 + tx];
    __syncthreads();
    out[(size_t)(tn * 16 + ty) * K + tk * 16 + tx] = f2bf(s[tx][ty]);
}

// ---------------- MFMA GEMM: C = act(A@W + bias) (+R)  --------------------
// A bf16 [M][K] row-major, Wt bf16 [N][K]. 256 thr = 4 waves.
// MTILE/64 = fragments per wave in M. K compile-time.
template<int ACT, int RES, int OBF, int QKV, int K, int MTILE>
__global__ __launch_bounds__(256) void gemm_mfma(const u16* __restrict__ A,
                                                 const u16* __restrict__ Wt,
                                                 const float* __restrict__ bias,
                                                 const float* __restrict__ R,
                                                 void* __restrict__ Cp,
                                                 u16* __restrict__ qb,
                                                 u16* __restrict__ kp,
                                                 u16* __restrict__ vp,
                                                 int N) {
    constexpr int SUB = MTILE / 64;          // fragments per wave in M
    int tid = threadIdx.x;
    int L = tid & 63, w = tid >> 6;
    int r = L & 15, g = L >> 4;
    int m0 = blockIdx.y * MTILE + w * (16 * SUB);
    int n0 = blockIdx.x * 64;

    f32x4 acc[SUB][4] = {};
    const u16* Ab = A + (size_t)(m0 + r) * K + g * 8;
    const u16* Wb = Wt + (size_t)(n0 + r) * K + g * 8;
    #pragma unroll 6
    for (int k0 = 0; k0 < K; k0 += 32) {
        s16x8 af[SUB];
        #pragma unroll
        for (int mi = 0; mi < SUB; ++mi)
            af[mi] = *(const s16x8*)(Ab + (size_t)mi * 16 * K + k0);
        #pragma unroll
        for (int nn = 0; nn < 4; ++nn) {
            s16x8 bf = *(const s16x8*)(Wb + (size_t)nn * 16 * K + k0);
            #pragma unroll
            for (int mi = 0; mi < SUB; ++mi)
                acc[mi][nn] = __builtin_amdgcn_mfma_f32_16x16x32_bf16(af[mi], bf, acc[mi][nn], 0, 0, 0);
        }
    }

    #pragma unroll
    for (int mi = 0; mi < SUB; ++mi)
    #pragma unroll
    for (int nn = 0; nn < 4; ++nn) {
        int cb = n0 + nn * 16;
        #pragma unroll
        for (int i = 0; i < 4; ++i) {
            int row = m0 + mi * 16 + g * 4 + i;
            float v = acc[mi][nn][i] + bias[cb + r];
            if (QKV) {
                int h  = cb / 96, c0 = cb % 96;
                int reg = c0 >> 5;               // 0=q, 1=k, 2=v
                if (reg == 0) {
                    v *= QS;
                    qb[(size_t)row * DIMC + h * 32 + (c0 & 31) + r] = f2bf(v);
                } else {
                    int b_ = row / LTOK, t = row - b_ * LTOK;
                    int T = t >> 5, it = t & 31;
                    int d = (c0 & 31) + r;
                    if (reg == 1) {
                        int which = (it >> 2) & 1;
                        int ik = ((it >> 3) << 2) | (it & 3);
                        int Lk = ((d >> 3) << 4) + ik;
                        kp[((size_t)(b_ * HEADS + h) * 40 + T) * 1024 + which * 512 + Lk * 8 + (d & 7)] = f2bf(v);
                    } else {
                        int Lv = ((it >> 3) << 4) + (d & 15);
                        vp[((size_t)(b_ * HEADS + h) * 40 + T) * 1024 + (d >> 4) * 512 + Lv * 8 + (it & 7)] = f2bf(v);
                    }
                }
            } else {
                if (ACT == 1) {
                    float u = v;
                    float y = 0.7978845608028654f * (u + 0.044715f * u * u * u);
                    float e2 = fexp2(y * 2.885390081777927f);   // 2*log2(e)
                    v = u - u * frcp(e2 + 1.0f);                // 0.5u(1+tanh(y))
                }
                if (RES) v += R[(size_t)row * N + cb + r];
                if (OBF) ((u16*)Cp)[(size_t)row * N + cb + r] = f2bf(v);
                else     ((float*)Cp)[(size_t)row * N + cb + r] = v;
            }
        }
    }
}

// ---- MFMA flash attention: LDS K/V, 64-key iterations, dbuf ---------------
// 960 blocks = (b 8) x (h 6) x (qg 20), XCD-chunk swizzled (batch innermost
// so the 8 batches of one (h,qg) share an XCD: bm L2-local). 4 waves/block,
// wave w owns q-rows [qg*64+w*16, +16). Per iteration: 64 keys (2 fragment
// tiles), 8 MFMA + 16 exp between barriers; 20 barriers total. Staging:
// wave w copies chunk (k/v = w>>1, tile-of-pair = w&1), 32B/thread, loads
// issued at iter start, ds_write after compute (write-late), dbuf 2x8KB.
__global__ __launch_bounds__(256) void attn_mfma(const u16* __restrict__ qb,
                                                 const u16* __restrict__ kp,
                                                 const u16* __restrict__ vp,
                                                 const u16* __restrict__ bm,
                                                 u16* __restrict__ ob) {
    __shared__ __align__(16) u16 kvs[2][2][2048];   // [dbuf][k/v][2 tiles] 16KB
    int tid = threadIdx.x;
    int L = tid & 63, w = tid >> 6;
    int r = L & 15, g = L >> 4;
    int L8 = L * 8;

    int bid = blockIdx.x;
    int work = (bid & 7) * 120 + (bid >> 3);     // 960 = 8 * 120
    int b  = work & 7;
    int hq = work >> 3;                          // 0..119
    int qt = (hq % 20) * 4 + w;                  // 16-row q-tile, 0..79
    int h  = hq / 20;

    s16x8 qf = *(const s16x8*)(qb + (size_t)(b * LTOK + qt * 16 + r) * DIMC + h * 32 + g * 8);

    // stage assignment: wave -> (k/v stream, tile of pair); 32B per thread
    int skv = w >> 1, half = w & 1;
    const u16* gs = (skv ? vp : kp) + (size_t)(b * HEADS + h) * 40 * 1024 + L8;
    u16* dst0 = &kvs[0][skv][half * 1024 + L8];
    u16* dst1 = &kvs[1][skv][half * 1024 + L8];

    const u16* bmr = bm + ((size_t)h * LTOK + qt * 16 + r) * LTOK + g * 8;

    f32x4 acc0 = {0.f, 0.f, 0.f, 0.f}, acc1 = {0.f, 0.f, 0.f, 0.f};
    float lsum = 0.f;

    // prologue: stage pair 0 into buf0; bias pair 0
    {
        int4 pA = *(const int4*)(gs + half * 1024);
        int4 pB = *(const int4*)(gs + half * 1024 + 512);
        *(int4*)dst0 = pA;
        *(int4*)(dst0 + 512) = pB;
    }
    int4 bv0 = *(const int4*)(bmr);
    int4 bv1 = *(const int4*)(bmr + 32);
    __syncthreads();

    #pragma unroll 1
    for (int T = 0; T < 20; ++T) {
        int4 nA, nB, nb0, nb1;
        if (T < 19) {
            nA  = *(const int4*)(gs + (size_t)(2 * T + 2 + half) * 1024);
            nB  = *(const int4*)(gs + (size_t)(2 * T + 2 + half) * 1024 + 512);
            nb0 = *(const int4*)(bmr + (size_t)(T + 1) * 64);
            nb1 = *(const int4*)(bmr + (size_t)(T + 1) * 64 + 32);
        }
        const u16* kb = &kvs[T & 1][0][0];
        const u16* vb = &kvs[T & 1][1][0];
        f32x4 z0, z1, z2, z3;
        z0[0] = bflo(bv0.x); z0[1] = bfhi(bv0.x); z0[2] = bflo(bv0.y); z0[3] = bfhi(bv0.y);
        z1[0] = bflo(bv0.z); z1[1] = bfhi(bv0.z); z1[2] = bflo(bv0.w); z1[3] = bfhi(bv0.w);
        z2[0] = bflo(bv1.x); z2[1] = bfhi(bv1.x); z2[2] = bflo(bv1.y); z2[3] = bfhi(bv1.y);
        z3[0] = bflo(bv1.z); z3[1] = bfhi(bv1.z); z3[2] = bflo(bv1.w); z3[3] = bfhi(bv1.w);

        s16x8 kf0 = *(const s16x8*)(kb + L8);
        s16x8 kf1 = *(const s16x8*)(kb + 512 + L8);
        s16x8 kf2 = *(const s16x8*)(kb + 1024 + L8);
        s16x8 kf3 = *(const s16x8*)(kb + 1536 + L8);
        __builtin_amdgcn_s_setprio(1);
        f32x4 s0 = __builtin_amdgcn_mfma_f32_16x16x32_bf16(kf0, qf, z0, 0, 0, 0);
        f32x4 s1 = __builtin_amdgcn_mfma_f32_16x16x32_bf16(kf1, qf, z1, 0, 0, 0);
        f32x4 s2 = __builtin_amdgcn_mfma_f32_16x16x32_bf16(kf2, qf, z2, 0, 0, 0);
        f32x4 s3 = __builtin_amdgcn_mfma_f32_16x16x32_bf16(kf3, qf, z3, 0, 0, 0);
        float p[16];
        #pragma unroll
        for (int j = 0; j < 4; ++j) {
            p[j]      = fexp2(s0[j]);
            p[4 + j]  = fexp2(s1[j]);
            p[8 + j]  = fexp2(s2[j]);
            p[12 + j] = fexp2(s3[j]);
        }
        float t0 = ((p[0] + p[1]) + (p[2] + p[3])) + ((p[4] + p[5]) + (p[6] + p[7]));
        float t1 = ((p[8] + p[9]) + (p[10] + p[11])) + ((p[12] + p[13]) + (p[14] + p[15]));
        lsum += t0 + t1;
        union { unsigned u[4]; s16x8 v; } pa, pb;
        #pragma unroll
        for (int j = 0; j < 4; ++j) {
            asm("v_cvt_pk_bf16_f32 %0, %1, %2" : "=v"(pa.u[j]) : "v"(p[2 * j]), "v"(p[2 * j + 1]));
            asm("v_cvt_pk_bf16_f32 %0, %1, %2" : "=v"(pb.u[j]) : "v"(p[8 + 2 * j]), "v"(p[9 + 2 * j]));
        }
        s16x8 v0 = *(const s16x8*)(vb + L8);
        s16x8 v1 = *(const s16x8*)(vb + 512 + L8);
        s16x8 v2 = *(const s16x8*)(vb + 1024 + L8);
        s16x8 v3 = *(const s16x8*)(vb + 1536 + L8);
        acc0 = __builtin_amdgcn_mfma_f32_16x16x32_bf16(pa.v, v0, acc0, 0, 0, 0);
        acc1 = __builtin_amdgcn_mfma_f32_16x16x32_bf16(pa.v, v1, acc1, 0, 0, 0);
        acc0 = __builtin_amdgcn_mfma_f32_16x16x32_bf16(pb.v, v2, acc0, 0, 0, 0);
        acc1 = __builtin_amdgcn_mfma_f32_16x16x32_bf16(pb.v, v3, acc1, 0, 0, 0);
        __builtin_amdgcn_s_setprio(0);

        if (T < 19) {
            u16* d = (T & 1) ? dst0 : dst1;
            *(int4*)d = nA;
            *(int4*)(d + 512) = nB;
            bv0 = nb0; bv1 = nb1;
        }
        __syncthreads();
    }

    float lr = lsum;
    lr += __shfl_xor(lr, 16);
    lr += __shfl_xor(lr, 32);
    #pragma unroll
    for (int i = 0; i < 4; ++i) {
        float linv = frcp(__shfl(lr, 4 * g + i));
        size_t orow = (size_t)(b * LTOK + qt * 16 + 4 * g + i) * DIMC + h * 32 + r;
        ob[orow]      = f2bf(acc0[i] * linv);
        ob[orow + 16] = f2bf(acc1[i] * linv);
    }
}

// ------- Depthwise 3x3 conv + BN + LayerNorm2 fused (wave per row) ---------
// Writes xm2 (f32, fc2 residual) and hbuf (bf16 LN2 output, fc1 input).
__global__ __launch_bounds__(256) void conv_ln_kernel(const float* __restrict__ xm,
                                                      const float* __restrict__ w,
                                                      const float* __restrict__ scale,
                                                      const float* __restrict__ bias,
                                                      const float* __restrict__ g2,
                                                      const float* __restrict__ b2,
                                                      float* __restrict__ xm2,
                                                      u16* __restrict__ y) {
    int row = blockIdx.x * 4 + (threadIdx.x >> 6);
    int lane = threadIdx.x & 63;
    int b = row / LTOK, t = row - b * LTOK;
    int H, W, base, y0, x0;
    if (t < 1024) { H = 32; W = 32; base = 0;    y0 = t >> 5;            x0 = t & 31; }
    else          { H = 16; W = 16; base = 1024; int tt = t - 1024; y0 = tt >> 4; x0 = tt & 15; }
    float a0 = 0.f, a1 = 0.f, a2 = 0.f;
    #pragma unroll
    for (int ky = 0; ky < 3; ++ky) {
        int yy = y0 + ky - 1;
        if (yy < 0 || yy >= H) continue;
        #pragma unroll
        for (int kx = 0; kx < 3; ++kx) {
            int xx = x0 + kx - 1;
            if (xx < 0 || xx >= W) continue;
            const float* xr = xm + (size_t)(b * LTOK + base + yy * W + xx) * DIMC;
            const float* wr = w + (ky * 3 + kx) * DIMC;
            a0 += wr[lane]       * xr[lane];
            a1 += wr[lane + 64]  * xr[lane + 64];
            a2 += wr[lane + 128] * xr[lane + 128];
        }
    }
    float v0 = a0 * scale[lane]       + bias[lane];
    float v1 = a1 * scale[lane + 64]  + bias[lane + 64];
    float v2 = a2 * scale[lane + 128] + bias[lane + 128];
    float* xr2 = xm2 + (size_t)row * DIMC;
    xr2[lane] = v0; xr2[lane + 64] = v1; xr2[lane + 128] = v2;
    float s = v0 + v1 + v2;
    float ss = v0 * v0 + v1 * v1 + v2 * v2;
    #pragma unroll
    for (int off = 32; off; off >>= 1) {
        s  += __shfl_xor(s, off);
        ss += __shfl_xor(ss, off);
    }
    float mu  = s * (1.0f / DIMC);
    float var = ss * (1.0f / DIMC) - mu * mu;
    float inv = rsqrtf(var + 1e-5f);
    u16* yr = y + (size_t)row * DIMC;
    yr[lane]       = f2bf((v0 - mu) * inv * g2[lane]       + b2[lane]);
    yr[lane + 64]  = f2bf((v1 - mu) * inv * g2[lane + 64]  + b2[lane + 64]);
    yr[lane + 128] = f2bf((v2 - mu) * inv * g2[lane + 128] + b2[lane + 128]);
}

// ---------------------------------------------------------------------------
extern "C" void kernel_launch(void* const* d_in, const int* in_sizes, int n_in,
                              void* d_out, int out_size, void* d_ws, size_t ws_size,
                              hipStream_t stream) {
    const float* xz       = (const float*)d_in[0];
    const int*   bidx     = (const int*)  d_in[1];
    const float* ln1_g    = (const float*)d_in[2];
    const float* ln1_b    = (const float*)d_in[3];
    const float* wqkv     = (const float*)d_in[4];
    const float* bqkv     = (const float*)d_in[5];
    const float* wproj    = (const float*)d_in[6];
    const float* bproj    = (const float*)d_in[7];
    const float* btab     = (const float*)d_in[8];
    const float* conv_w   = (const float*)d_in[9];
    const float* bn_scale = (const float*)d_in[10];
    const float* bn_bias  = (const float*)d_in[11];
    const float* ln2_g    = (const float*)d_in[12];
    const float* ln2_b    = (const float*)d_in[13];
    const float* w1       = (const float*)d_in[14];
    const float* b1       = (const float*)d_in[15];
    const float* w2       = (const float*)d_in[16];
    const float* b2       = (const float*)d_in[17];
    int n_off = in_sizes[8] / HEADS;
    float* out = (float*)d_out;

    // ---- workspace layout (bytes), liveness overlays; peak 40.2 MB ----
    char* wsb = (char*)d_ws;
    u16*  hbuf   = (u16*)(wsb + 0);                    // ln out; ob overlays
    u16*  ob     = (u16*)(wsb + 0);
    u16*  wqkvT  = (u16*)(wsb + 3932160);
    u16*  wprojT = (u16*)(wsb + 4153344);
    u16*  w1T    = (u16*)(wsb + 4227072);
    u16*  w2T    = (u16*)(wsb + 4521984);
    u16*  bm     = (u16*)(wsb + 4816896);              // 19.6 MB; hid overlays
    u16*  hid    = (u16*)(wsb + 4816896);
    u16*  kp     = (u16*)(wsb + 24477696);
    u16*  vp     = (u16*)(wsb + 28409856);
    float* xm2   = (float*)(wsb + 24477696);           // overlays kp/vp
    u16*  qb     = (u16*)(wsb + 32342016);
    float* xm    = (float*)(wsb + 32342016);           // overlays qb

    // 1) preprocess: weight transposes + bias matrix + LN1 (merged)
    pre_kernel<<<1728 + LTOK * LTOK / 1024 + NROWS / 4, 256, 0, stream>>>(
        wqkv, wproj, w1, w2, wqkvT, wprojT, w1T, w2T, bidx, btab, n_off, bm,
        xz, ln1_g, ln1_b, hbuf);
    // 2) QKV GEMM (MTILE=256), scattering q/K/V into attention layouts
    gemm_mfma<0,0,0,1,DIMC,256><<<dim3(576 / 64, NROWS / 256), 256, 0, stream>>>(
        hbuf, wqkvT, bqkv, nullptr, nullptr, qb, kp, vp, 3 * DIMC);
    // 3) attention (64-key iterations, dbuf LDS, XCD-swizzled)
    attn_mfma<<<960, 256, 0, stream>>>(qb, kp, vp, bm, ob);
    // 4) proj + residual(xz) -> xm f32
    gemm_mfma<0,1,0,0,DIMC,128><<<dim3(DIMC / 64, NROWS / 128), 256, 0, stream>>>(
        ob, wprojT, bproj, xz, xm, nullptr, nullptr, nullptr, DIMC);
    // 5) depthwise conv + BN + LN2 -> xm2 f32 + hbuf bf16
    conv_ln_kernel<<<NROWS / 4, 256, 0, stream>>>(
        xm, conv_w, bn_scale, bn_bias, ln2_g, ln2_b, xm2, hbuf);
    // 6) MLP fc1 + GELU (MTILE=256) -> hid bf16
    gemm_mfma<1,0,1,0,DIMC,256><<<dim3(HID / 64, NROWS / 256), 256, 0, stream>>>(
        hbuf, w1T, b1, nullptr, hid, nullptr, nullptr, nullptr, HID);
    // 7) MLP fc2 + residual(xm2) -> out f32
    gemm_mfma<0,1,0,0,HID,128><<<dim3(DIMC / 64, NROWS / 128), 256, 0, stream>>>(
        hid, w2T, b2, xm2, out, nullptr, nullptr, nullptr, DIMC);
}

// Round 10
// 124.156 us; speedup vs baseline: 1.2505x; 1.0378x over previous
//
#include <hip/hip_runtime.h>
#include <hip/hip_bf16.h>

#define BATCH 8
#define LTOK 1280
#define DIMC 192
#define HEADS 6
#define KD 32
#define HID 768
#define NROWS (BATCH*LTOK)   // 10240

typedef short s16x8 __attribute__((ext_vector_type(8)));
typedef float f32x4 __attribute__((ext_vector_type(4)));
typedef unsigned short u16;

// q pre-scale: 32^-0.5 * log2(e)  (softmax runs in exp2 domain)
#define QS (0.17677669529663687f * 1.4426950408889634f)
#define L2E 1.4426950408889634f

__device__ __forceinline__ u16 f2bf(float x) {
    unsigned u = __float_as_uint(x);
    u = (u + 0x7FFFu + ((u >> 16) & 1u)) >> 16;
    return (u16)u;
}
__device__ __forceinline__ float bflo(unsigned u) { return __uint_as_float(u << 16); }
__device__ __forceinline__ float bfhi(unsigned u) { return __uint_as_float(u & 0xffff0000u); }
__device__ __forceinline__ float fexp2(float x) { float r; asm("v_exp_f32 %0, %1" : "=v"(r) : "v"(x)); return r; }
__device__ __forceinline__ float frcp(float x)  { float r; asm("v_rcp_f32 %0, %1" : "=v"(r) : "v"(x)); return r; }

// --- Preprocess (merged): weight transpose + fragment-packed bias + LN1 ----
// blocks [0,1728): W[K][N] f32 -> Wt[N][K] bf16
// blocks [1728,11328): bmp[h][qt][T][half][lane][8] = bf16(tab*log2e)
//   (MFMA-fragment order: attention reads one contiguous 1KB int4/wave/iter)
// blocks [11328,13888): LN1 of xz -> hbuf bf16 (4 rows/block)
__global__ __launch_bounds__(256) void pre_kernel(const float* w0, const float* w1,
                                                  const float* w2, const float* w3,
                                                  u16* o0, u16* o1, u16* o2, u16* o3,
                                                  const int* __restrict__ bidx,
                                                  const float* __restrict__ btab,
                                                  int n_off, u16* __restrict__ bmp,
                                                  const float* __restrict__ xz,
                                                  const float* __restrict__ ln1g,
                                                  const float* __restrict__ ln1b,
                                                  u16* __restrict__ hbuf) {
    __shared__ float s[16][17];
    int f = blockIdx.x;
    if (f >= 11328) {                      // LN1
        int row = (f - 11328) * 4 + (threadIdx.x >> 6);
        int lane = threadIdx.x & 63;
        const float* xr = xz + (size_t)row * DIMC;
        float v0 = xr[lane], v1 = xr[lane + 64], v2 = xr[lane + 128];
        float sm = v0 + v1 + v2;
        float ss = v0 * v0 + v1 * v1 + v2 * v2;
        #pragma unroll
        for (int off = 32; off; off >>= 1) {
            sm += __shfl_xor(sm, off);
            ss += __shfl_xor(ss, off);
        }
        float mu  = sm * (1.0f / DIMC);
        float var = ss * (1.0f / DIMC) - mu * mu;
        float inv = rsqrtf(var + 1e-5f);
        u16* yr = hbuf + (size_t)row * DIMC;
        yr[lane]       = f2bf((v0 - mu) * inv * ln1g[lane]       + ln1b[lane]);
        yr[lane + 64]  = f2bf((v1 - mu) * inv * ln1g[lane + 64]  + ln1b[lane + 64]);
        yr[lane + 128] = f2bf((v2 - mu) * inv * ln1g[lane + 128] + ln1b[lane + 128]);
        return;
    }
    if (f >= 1728) {                       // fragment-packed bias matrix
        int fb = f - 1728;                 // (qt, T) major, h minor -> bidx L2 reuse
        int qt = fb / 120;
        int rem = fb - qt * 120;
        int T = rem / 6, h = rem - (rem / 6) * 6;
        int tid = threadIdx.x;
        int half = tid >> 7, L = (tid >> 1) & 63, j4 = (tid & 1) * 4;
        int n = qt * 16 + (L & 15);
        int m = T * 64 + half * 32 + ((L >> 4) << 3) + j4;
        int4 iv = *(const int4*)(bidx + (size_t)n * LTOK + m);
        const float* tab = btab + (size_t)h * n_off;
        ushort4 o;
        o.x = f2bf(tab[iv.x] * L2E);
        o.y = f2bf(tab[iv.y] * L2E);
        o.z = f2bf(tab[iv.z] * L2E);
        o.w = f2bf(tab[iv.w] * L2E);
        *(ushort4*)(bmp + (size_t)(h * 80 + qt) * 20480 + T * 1024 + tid * 4) = o;
        return;
    }
    const float* in; u16* out; int K, N, tn, tk;
    if (f < 432)       { in = w0; out = o0; K = 192; N = 576; int r = f;        tn = r % 36; tk = r / 36; }
    else if (f < 576)  { in = w1; out = o1; K = 192; N = 192; int r = f - 432;  tn = r % 12; tk = r / 12; }
    else if (f < 1152) { in = w2; out = o2; K = 192; N = 768; int r = f - 576;  tn = r % 48; tk = r / 48; }
    else               { in = w3; out = o3; K = 768; N = 192; int r = f - 1152; tn = r % 12; tk = r / 12; }
    int tx = threadIdx.x & 15, ty = threadIdx.x >> 4;
    s[ty][tx] = in[(size_t)(tk * 16 + ty) * N + tn * 16 + tx];
    __syncthreads();
    out[(size_t)(tn * 16 + ty) * K + tk * 16 + tx] = f2bf(s[tx][ty]);
}

// ---------------- MFMA GEMM: C = act(A@W + bias) (+R)  --------------------
// A bf16 [M][K] row-major, Wt bf16 [N][K]. 256 thr = 4 waves.
// MTILE/64 = fragments per wave in M. K compile-time.
template<int ACT, int RES, int OBF, int QKV, int K, int MTILE>
__global__ __launch_bounds__(256) void gemm_mfma(const u16* __restrict__ A,
                                                 const u16* __restrict__ Wt,
                                                 const float* __restrict__ bias,
                                                 const float* __restrict__ R,
                                                 void* __restrict__ Cp,
                                                 u16* __restrict__ qb,
                                                 u16* __restrict__ kp,
                                                 u16* __restrict__ vp,
                                                 int N) {
    constexpr int SUB = MTILE / 64;          // fragments per wave in M
    int tid = threadIdx.x;
    int L = tid & 63, w = tid >> 6;
    int r = L & 15, g = L >> 4;
    int m0 = blockIdx.y * MTILE + w * (16 * SUB);
    int n0 = blockIdx.x * 64;

    f32x4 acc[SUB][4] = {};
    const u16* Ab = A + (size_t)(m0 + r) * K + g * 8;
    const u16* Wb = Wt + (size_t)(n0 + r) * K + g * 8;
    #pragma unroll 6
    for (int k0 = 0; k0 < K; k0 += 32) {
        s16x8 af[SUB];
        #pragma unroll
        for (int mi = 0; mi < SUB; ++mi)
            af[mi] = *(const s16x8*)(Ab + (size_t)mi * 16 * K + k0);
        #pragma unroll
        for (int nn = 0; nn < 4; ++nn) {
            s16x8 bf = *(const s16x8*)(Wb + (size_t)nn * 16 * K + k0);
            #pragma unroll
            for (int mi = 0; mi < SUB; ++mi)
                acc[mi][nn] = __builtin_amdgcn_mfma_f32_16x16x32_bf16(af[mi], bf, acc[mi][nn], 0, 0, 0);
        }
    }

    #pragma unroll
    for (int mi = 0; mi < SUB; ++mi)
    #pragma unroll
    for (int nn = 0; nn < 4; ++nn) {
        int cb = n0 + nn * 16;
        #pragma unroll
        for (int i = 0; i < 4; ++i) {
            int row = m0 + mi * 16 + g * 4 + i;
            float v = acc[mi][nn][i] + bias[cb + r];
            if (QKV) {
                int h  = cb / 96, c0 = cb % 96;
                int reg = c0 >> 5;               // 0=q, 1=k, 2=v
                if (reg == 0) {
                    v *= QS;
                    qb[(size_t)row * DIMC + h * 32 + (c0 & 31) + r] = f2bf(v);
                } else {
                    int b_ = row / LTOK, t = row - b_ * LTOK;
                    int T = t >> 5, it = t & 31;
                    int d = (c0 & 31) + r;
                    if (reg == 1) {
                        int which = (it >> 2) & 1;
                        int ik = ((it >> 3) << 2) | (it & 3);
                        int Lk = ((d >> 3) << 4) + ik;
                        kp[((size_t)(b_ * HEADS + h) * 40 + T) * 1024 + which * 512 + Lk * 8 + (d & 7)] = f2bf(v);
                    } else {
                        int Lv = ((it >> 3) << 4) + (d & 15);
                        vp[((size_t)(b_ * HEADS + h) * 40 + T) * 1024 + (d >> 4) * 512 + Lv * 8 + (it & 7)] = f2bf(v);
                    }
                }
            } else {
                if (ACT == 1) {
                    float u = v;
                    float y = 0.7978845608028654f * (u + 0.044715f * u * u * u);
                    float e2 = fexp2(y * 2.885390081777927f);   // 2*log2(e)
                    v = u - u * frcp(e2 + 1.0f);                // 0.5u(1+tanh(y))
                }
                if (RES) v += R[(size_t)row * N + cb + r];
                if (OBF) ((u16*)Cp)[(size_t)row * N + cb + r] = f2bf(v);
                else     ((float*)Cp)[(size_t)row * N + cb + r] = v;
            }
        }
    }
}

// ---- MFMA flash attention: LDS K/V, 64-key iters, QK-ahead pipeline -------
// 960 blocks = (b 8) x (h 6) x (qg 20), XCD-chunk swizzled (batch innermost:
// bmp/kp L2 locality). 4 waves/block, wave w owns q-rows [qg*64+w*16, +16).
// Pipeline: QK(T+1) issues right after the barrier of iter T (its ds_read +
// MFMA latency overlaps iter T+1's prefetch/exp issue); exp(T)/PV(T) consume
// S computed one stage earlier. Bias reads are ONE contiguous 1KB int4/wave
// per 32-key half (fragment-packed bmp). dbuf LDS 2x8KB, 1 barrier/iter.
__global__ __launch_bounds__(256) void attn_mfma(const u16* __restrict__ qb,
                                                 const u16* __restrict__ kp,
                                                 const u16* __restrict__ vp,
                                                 const u16* __restrict__ bmp,
                                                 u16* __restrict__ ob) {
    __shared__ __align__(16) u16 kvs[2][2][2048];   // [dbuf][k/v][2 tiles] 16KB
    int tid = threadIdx.x;
    int L = tid & 63, w = tid >> 6;
    int r = L & 15, g = L >> 4;
    int L8 = L * 8;

    int bid = blockIdx.x;
    int work = (bid & 7) * 120 + (bid >> 3);     // 960 = 8 * 120
    int b  = work & 7;
    int hq = work >> 3;                          // 0..119
    int qt = (hq % 20) * 4 + w;                  // 16-row q-tile, 0..79
    int h  = hq / 20;

    s16x8 qf = *(const s16x8*)(qb + (size_t)(b * LTOK + qt * 16 + r) * DIMC + h * 32 + g * 8);

    // stage assignment: wave -> (k/v stream, tile of pair); 32B per thread
    int skv = w >> 1, half = w & 1;
    const u16* gs = (skv ? vp : kp) + (size_t)(b * HEADS + h) * 40 * 1024 + L8;
    u16* dst0 = &kvs[0][skv][half * 1024 + L8];
    u16* dst1 = &kvs[1][skv][half * 1024 + L8];

    const u16* bmr = bmp + (size_t)(h * 80 + qt) * 20480 + L8;   // fragment-packed

    f32x4 acc0 = {0.f, 0.f, 0.f, 0.f}, acc1 = {0.f, 0.f, 0.f, 0.f};
    float lsum = 0.f;

    // prologue: stage pair 0 -> buf0, bias pair 0, barrier, QK(0)
    {
        int4 pA = *(const int4*)(gs + half * 1024);
        int4 pB = *(const int4*)(gs + half * 1024 + 512);
        *(int4*)dst0 = pA;
        *(int4*)(dst0 + 512) = pB;
    }
    int4 cb0 = *(const int4*)(bmr);
    int4 cb1 = *(const int4*)(bmr + 512);
    __syncthreads();

    f32x4 s0, s1, s2, s3;
    {
        const u16* kb = &kvs[0][0][0];
        f32x4 z0, z1, z2, z3;
        z0[0] = bflo(cb0.x); z0[1] = bfhi(cb0.x); z0[2] = bflo(cb0.y); z0[3] = bfhi(cb0.y);
        z1[0] = bflo(cb0.z); z1[1] = bfhi(cb0.z); z1[2] = bflo(cb0.w); z1[3] = bfhi(cb0.w);
        z2[0] = bflo(cb1.x); z2[1] = bfhi(cb1.x); z2[2] = bflo(cb1.y); z2[3] = bfhi(cb1.y);
        z3[0] = bflo(cb1.z); z3[1] = bfhi(cb1.z); z3[2] = bflo(cb1.w); z3[3] = bfhi(cb1.w);
        s16x8 kf0 = *(const s16x8*)(kb + L8);
        s16x8 kf1 = *(const s16x8*)(kb + 512 + L8);
        s16x8 kf2 = *(const s16x8*)(kb + 1024 + L8);
        s16x8 kf3 = *(const s16x8*)(kb + 1536 + L8);
        s0 = __builtin_amdgcn_mfma_f32_16x16x32_bf16(kf0, qf, z0, 0, 0, 0);
        s1 = __builtin_amdgcn_mfma_f32_16x16x32_bf16(kf1, qf, z1, 0, 0, 0);
        s2 = __builtin_amdgcn_mfma_f32_16x16x32_bf16(kf2, qf, z2, 0, 0, 0);
        s3 = __builtin_amdgcn_mfma_f32_16x16x32_bf16(kf3, qf, z3, 0, 0, 0);
    }

    #pragma unroll 1
    for (int T = 0; T < 20; ++T) {
        int4 nA, nB, nb0, nb1;
        if (T < 19) {
            nA  = *(const int4*)(gs + (size_t)(2 * T + 2 + half) * 1024);
            nB  = *(const int4*)(gs + (size_t)(2 * T + 2 + half) * 1024 + 512);
            nb0 = *(const int4*)(bmr + (size_t)(T + 1) * 1024);
            nb1 = *(const int4*)(bmr + (size_t)(T + 1) * 1024 + 512);
        }
        // exp(T) on S computed one stage earlier
        __builtin_amdgcn_s_setprio(1);
        float p[16];
        #pragma unroll
        for (int j = 0; j < 4; ++j) {
            p[j]      = fexp2(s0[j]);
            p[4 + j]  = fexp2(s1[j]);
            p[8 + j]  = fexp2(s2[j]);
            p[12 + j] = fexp2(s3[j]);
        }
        float t0 = ((p[0] + p[1]) + (p[2] + p[3])) + ((p[4] + p[5]) + (p[6] + p[7]));
        float t1 = ((p[8] + p[9]) + (p[10] + p[11])) + ((p[12] + p[13]) + (p[14] + p[15]));
        lsum += t0 + t1;
        union { unsigned u[4]; s16x8 v; } pa, pb;
        #pragma unroll
        for (int j = 0; j < 4; ++j) {
            asm("v_cvt_pk_bf16_f32 %0, %1, %2" : "=v"(pa.u[j]) : "v"(p[2 * j]), "v"(p[2 * j + 1]));
            asm("v_cvt_pk_bf16_f32 %0, %1, %2" : "=v"(pb.u[j]) : "v"(p[8 + 2 * j]), "v"(p[9 + 2 * j]));
        }
        // PV(T) from buf[T&1]
        const u16* vb = &kvs[T & 1][1][0];
        s16x8 v0 = *(const s16x8*)(vb + L8);
        s16x8 v1 = *(const s16x8*)(vb + 512 + L8);
        s16x8 v2 = *(const s16x8*)(vb + 1024 + L8);
        s16x8 v3 = *(const s16x8*)(vb + 1536 + L8);
        acc0 = __builtin_amdgcn_mfma_f32_16x16x32_bf16(pa.v, v0, acc0, 0, 0, 0);
        acc1 = __builtin_amdgcn_mfma_f32_16x16x32_bf16(pa.v, v1, acc1, 0, 0, 0);
        acc0 = __builtin_amdgcn_mfma_f32_16x16x32_bf16(pb.v, v2, acc0, 0, 0, 0);
        acc1 = __builtin_amdgcn_mfma_f32_16x16x32_bf16(pb.v, v3, acc1, 0, 0, 0);
        __builtin_amdgcn_s_setprio(0);

        if (T < 19) {
            u16* d = (T & 1) ? dst0 : dst1;      // buf[(T+1)&1]
            *(int4*)d = nA;
            *(int4*)(d + 512) = nB;
        }
        __syncthreads();
        if (T < 19) {
            // QK(T+1): issues now, results consumed next iteration
            const u16* kb = &kvs[(T + 1) & 1][0][0];
            f32x4 z0, z1, z2, z3;
            z0[0] = bflo(nb0.x); z0[1] = bfhi(nb0.x); z0[2] = bflo(nb0.y); z0[3] = bfhi(nb0.y);
            z1[0] = bflo(nb0.z); z1[1] = bfhi(nb0.z); z1[2] = bflo(nb0.w); z1[3] = bfhi(nb0.w);
            z2[0] = bflo(nb1.x); z2[1] = bfhi(nb1.x); z2[2] = bflo(nb1.y); z2[3] = bfhi(nb1.y);
            z3[0] = bflo(nb1.z); z3[1] = bfhi(nb1.z); z3[2] = bflo(nb1.w); z3[3] = bfhi(nb1.w);
            s16x8 kf0 = *(const s16x8*)(kb + L8);
            s16x8 kf1 = *(const s16x8*)(kb + 512 + L8);
            s16x8 kf2 = *(const s16x8*)(kb + 1024 + L8);
            s16x8 kf3 = *(const s16x8*)(kb + 1536 + L8);
            __builtin_amdgcn_s_setprio(1);
            s0 = __builtin_amdgcn_mfma_f32_16x16x32_bf16(kf0, qf, z0, 0, 0, 0);
            s1 = __builtin_amdgcn_mfma_f32_16x16x32_bf16(kf1, qf, z1, 0, 0, 0);
            s2 = __builtin_amdgcn_mfma_f32_16x16x32_bf16(kf2, qf, z2, 0, 0, 0);
            s3 = __builtin_amdgcn_mfma_f32_16x16x32_bf16(kf3, qf, z3, 0, 0, 0);
            __builtin_amdgcn_s_setprio(0);
        }
    }

    float lr = lsum;
    lr += __shfl_xor(lr, 16);
    lr += __shfl_xor(lr, 32);
    #pragma unroll
    for (int i = 0; i < 4; ++i) {
        float linv = frcp(__shfl(lr, 4 * g + i));
        size_t orow = (size_t)(b * LTOK + qt * 16 + 4 * g + i) * DIMC + h * 32 + r;
        ob[orow]      = f2bf(acc0[i] * linv);
        ob[orow + 16] = f2bf(acc1[i] * linv);
    }
}

// ------- Depthwise 3x3 conv + BN + LayerNorm2 fused (wave per row) ---------
// Writes xm2 (f32, fc2 residual) and hbuf (bf16 LN2 output, fc1 input).
__global__ __launch_bounds__(256) void conv_ln_kernel(const float* __restrict__ xm,
                                                      const float* __restrict__ w,
                                                      const float* __restrict__ scale,
                                                      const float* __restrict__ bias,
                                                      const float* __restrict__ g2,
                                                      const float* __restrict__ b2,
                                                      float* __restrict__ xm2,
                                                      u16* __restrict__ y) {
    int row = blockIdx.x * 4 + (threadIdx.x >> 6);
    int lane = threadIdx.x & 63;
    int b = row / LTOK, t = row - b * LTOK;
    int H, W, base, y0, x0;
    if (t < 1024) { H = 32; W = 32; base = 0;    y0 = t >> 5;            x0 = t & 31; }
    else          { H = 16; W = 16; base = 1024; int tt = t - 1024; y0 = tt >> 4; x0 = tt & 15; }
    float a0 = 0.f, a1 = 0.f, a2 = 0.f;
    #pragma unroll
    for (int ky = 0; ky < 3; ++ky) {
        int yy = y0 + ky - 1;
        if (yy < 0 || yy >= H) continue;
        #pragma unroll
        for (int kx = 0; kx < 3; ++kx) {
            int xx = x0 + kx - 1;
            if (xx < 0 || xx >= W) continue;
            const float* xr = xm + (size_t)(b * LTOK + base + yy * W + xx) * DIMC;
            const float* wr = w + (ky * 3 + kx) * DIMC;
            a0 += wr[lane]       * xr[lane];
            a1 += wr[lane + 64]  * xr[lane + 64];
            a2 += wr[lane + 128] * xr[lane + 128];
        }
    }
    float v0 = a0 * scale[lane]       + bias[lane];
    float v1 = a1 * scale[lane + 64]  + bias[lane + 64];
    float v2 = a2 * scale[lane + 128] + bias[lane + 128];
    float* xr2 = xm2 + (size_t)row * DIMC;
    xr2[lane] = v0; xr2[lane + 64] = v1; xr2[lane + 128] = v2;
    float s = v0 + v1 + v2;
    float ss = v0 * v0 + v1 * v1 + v2 * v2;
    #pragma unroll
    for (int off = 32; off; off >>= 1) {
        s  += __shfl_xor(s, off);
        ss += __shfl_xor(ss, off);
    }
    float mu  = s * (1.0f / DIMC);
    float var = ss * (1.0f / DIMC) - mu * mu;
    float inv = rsqrtf(var + 1e-5f);
    u16* yr = y + (size_t)row * DIMC;
    yr[lane]       = f2bf((v0 - mu) * inv * g2[lane]       + b2[lane]);
    yr[lane + 64]  = f2bf((v1 - mu) * inv * g2[lane + 64]  + b2[lane + 64]);
    yr[lane + 128] = f2bf((v2 - mu) * inv * g2[lane + 128] + b2[lane + 128]);
}

// ---------------------------------------------------------------------------
extern "C" void kernel_launch(void* const* d_in, const int* in_sizes, int n_in,
                              void* d_out, int out_size, void* d_ws, size_t ws_size,
                              hipStream_t stream) {
    const float* xz       = (const float*)d_in[0];
    const int*   bidx     = (const int*)  d_in[1];
    const float* ln1_g    = (const float*)d_in[2];
    const float* ln1_b    = (const float*)d_in[3];
    const float* wqkv     = (const float*)d_in[4];
    const float* bqkv     = (const float*)d_in[5];
    const float* wproj    = (const float*)d_in[6];
    const float* bproj    = (const float*)d_in[7];
    const float* btab     = (const float*)d_in[8];
    const float* conv_w   = (const float*)d_in[9];
    const float* bn_scale = (const float*)d_in[10];
    const float* bn_bias  = (const float*)d_in[11];
    const float* ln2_g    = (const float*)d_in[12];
    const float* ln2_b    = (const float*)d_in[13];
    const float* w1       = (const float*)d_in[14];
    const float* b1       = (const float*)d_in[15];
    const float* w2       = (const float*)d_in[16];
    const float* b2       = (const float*)d_in[17];
    int n_off = in_sizes[8] / HEADS;
    float* out = (float*)d_out;

    // ---- workspace layout (bytes), liveness overlays; peak 40.2 MB ----
    char* wsb = (char*)d_ws;
    u16*  hbuf   = (u16*)(wsb + 0);                    // ln out; ob overlays
    u16*  ob     = (u16*)(wsb + 0);
    u16*  wqkvT  = (u16*)(wsb + 3932160);
    u16*  wprojT = (u16*)(wsb + 4153344);
    u16*  w1T    = (u16*)(wsb + 4227072);
    u16*  w2T    = (u16*)(wsb + 4521984);
    u16*  bmp    = (u16*)(wsb + 4816896);              // 19.6 MB; hid overlays
    u16*  hid    = (u16*)(wsb + 4816896);
    u16*  kp     = (u16*)(wsb + 24477696);
    u16*  vp     = (u16*)(wsb + 28409856);
    float* xm2   = (float*)(wsb + 24477696);           // overlays kp/vp
    u16*  qb     = (u16*)(wsb + 32342016);
    float* xm    = (float*)(wsb + 32342016);           // overlays qb

    // 1) preprocess: weight transposes + fragment-packed bias + LN1 (merged)
    pre_kernel<<<13888, 256, 0, stream>>>(
        wqkv, wproj, w1, w2, wqkvT, wprojT, w1T, w2T, bidx, btab, n_off, bmp,
        xz, ln1_g, ln1_b, hbuf);
    // 2) QKV GEMM (MTILE=256), scattering q/K/V into attention layouts
    gemm_mfma<0,0,0,1,DIMC,256><<<dim3(576 / 64, NROWS / 256), 256, 0, stream>>>(
        hbuf, wqkvT, bqkv, nullptr, nullptr, qb, kp, vp, 3 * DIMC);
    // 3) attention (QK-ahead pipeline, dbuf LDS, XCD-swizzled)
    attn_mfma<<<960, 256, 0, stream>>>(qb, kp, vp, bmp, ob);
    // 4) proj + residual(xz) -> xm f32
    gemm_mfma<0,1,0,0,DIMC,128><<<dim3(DIMC / 64, NROWS / 128), 256, 0, stream>>>(
        ob, wprojT, bproj, xz, xm, nullptr, nullptr, nullptr, DIMC);
    // 5) depthwise conv + BN + LN2 -> xm2 f32 + hbuf bf16
    conv_ln_kernel<<<NROWS / 4, 256, 0, stream>>>(
        xm, conv_w, bn_scale, bn_bias, ln2_g, ln2_b, xm2, hbuf);
    // 6) MLP fc1 + GELU (MTILE=256) -> hid bf16
    gemm_mfma<1,0,1,0,DIMC,256><<<dim3(HID / 64, NROWS / 256), 256, 0, stream>>>(
        hbuf, w1T, b1, nullptr, hid, nullptr, nullptr, nullptr, HID);
    // 7) MLP fc2 + residual(xm2) -> out f32
    gemm_mfma<0,1,0,0,HID,128><<<dim3(DIMC / 64, NROWS / 128), 256, 0, stream>>>(
        hid, w2T, b2, xm2, out, nullptr, nullptr, nullptr, DIMC);
}

// Round 11
// 120.533 us; speedup vs baseline: 1.2880x; 1.0301x over previous
//
#include <hip/hip_runtime.h>
#include <hip/hip_bf16.h>

#define BATCH 8
#define LTOK 1280
#define DIMC 192
#define HEADS 6
#define KD 32
#define HID 768
#define NROWS (BATCH*LTOK)   // 10240

typedef short s16x8 __attribute__((ext_vector_type(8)));
typedef float f32x4 __attribute__((ext_vector_type(4)));
typedef unsigned short u16;

// q pre-scale: 32^-0.5 * log2(e)  (softmax runs in exp2 domain)
#define QS (0.17677669529663687f * 1.4426950408889634f)
#define L2E 1.4426950408889634f

__device__ __forceinline__ u16 f2bf(float x) {
    unsigned u = __float_as_uint(x);
    u = (u + 0x7FFFu + ((u >> 16) & 1u)) >> 16;
    return (u16)u;
}
__device__ __forceinline__ float bflo(unsigned u) { return __uint_as_float(u << 16); }
__device__ __forceinline__ float bfhi(unsigned u) { return __uint_as_float(u & 0xffff0000u); }
__device__ __forceinline__ float fexp2(float x) { float r; asm("v_exp_f32 %0, %1" : "=v"(r) : "v"(x)); return r; }
__device__ __forceinline__ float frcp(float x)  { float r; asm("v_rcp_f32 %0, %1" : "=v"(r) : "v"(x)); return r; }

// --- pre_a: ONLY what QKV needs — wqkv transpose + LN1 ---------------------
// blocks [0,432): wqkv[K=192][N=576] f32 -> wqkvT[N][K] bf16
// blocks [432,2992): LN1 of xz -> hbuf bf16 (4 rows/block)
__global__ __launch_bounds__(256) void pre_a(const float* __restrict__ w0,
                                             u16* __restrict__ o0,
                                             const float* __restrict__ xz,
                                             const float* __restrict__ ln1g,
                                             const float* __restrict__ ln1b,
                                             u16* __restrict__ hbuf) {
    __shared__ float s[16][17];
    int f = blockIdx.x;
    if (f >= 432) {                        // LN1
        int row = (f - 432) * 4 + (threadIdx.x >> 6);
        int lane = threadIdx.x & 63;
        const float* xr = xz + (size_t)row * DIMC;
        float v0 = xr[lane], v1 = xr[lane + 64], v2 = xr[lane + 128];
        float sm = v0 + v1 + v2;
        float ss = v0 * v0 + v1 * v1 + v2 * v2;
        #pragma unroll
        for (int off = 32; off; off >>= 1) {
            sm += __shfl_xor(sm, off);
            ss += __shfl_xor(ss, off);
        }
        float mu  = sm * (1.0f / DIMC);
        float var = ss * (1.0f / DIMC) - mu * mu;
        float inv = rsqrtf(var + 1e-5f);
        u16* yr = hbuf + (size_t)row * DIMC;
        yr[lane]       = f2bf((v0 - mu) * inv * ln1g[lane]       + ln1b[lane]);
        yr[lane + 64]  = f2bf((v1 - mu) * inv * ln1g[lane + 64]  + ln1b[lane + 64]);
        yr[lane + 128] = f2bf((v2 - mu) * inv * ln1g[lane + 128] + ln1b[lane + 128]);
        return;
    }
    int tn = f % 36, tk = f / 36;
    int tx = threadIdx.x & 15, ty = threadIdx.x >> 4;
    s[ty][tx] = w0[(size_t)(tk * 16 + ty) * 576 + tn * 16 + tx];
    __syncthreads();
    o0[(size_t)(tn * 16 + ty) * 192 + tk * 16 + tx] = f2bf(s[tx][ty]);
}

// --- qkv_mega: QKV GEMM + fragment-packed bias matrix + late wtrans --------
// blocks [0,360): QKV GEMM (MTILE=256), q/K/V scattered to attn layouts
// blocks [360,9960): bmp[h][qt][T][half][lane][8] = bf16(tab*log2e)
// blocks [9960,11256): wproj/w1/w2 transposes (needed only by later kernels)
// The bmp/wtrans blocks fill the CUs the 360-block GEMM leaves idle.
__global__ __launch_bounds__(256) void qkv_mega(const u16* __restrict__ A,
                                                const u16* __restrict__ Wt,
                                                const float* __restrict__ bias,
                                                u16* __restrict__ qb,
                                                u16* __restrict__ kp,
                                                u16* __restrict__ vp,
                                                const int* __restrict__ bidx,
                                                const float* __restrict__ btab,
                                                int n_off, u16* __restrict__ bmp,
                                                const float* __restrict__ wp,
                                                const float* __restrict__ wf1,
                                                const float* __restrict__ wf2,
                                                u16* __restrict__ op,
                                                u16* __restrict__ of1,
                                                u16* __restrict__ of2) {
    int bid = blockIdx.x;
    if (bid >= 9960) {                     // late weight transposes
        __shared__ float s[16][17];
        int f2 = bid - 9960;
        const float* in; u16* out; int K, N, tn, tk;
        if (f2 < 144)      { in = wp;  out = op;  K = 192; N = 192; tn = f2 % 12; tk = f2 / 12; }
        else if (f2 < 720) { in = wf1; out = of1; K = 192; N = 768; int q = f2 - 144; tn = q % 48; tk = q / 48; }
        else               { in = wf2; out = of2; K = 768; N = 192; int q = f2 - 720; tn = q % 12; tk = q / 12; }
        int tx = threadIdx.x & 15, ty = threadIdx.x >> 4;
        s[ty][tx] = in[(size_t)(tk * 16 + ty) * N + tn * 16 + tx];
        __syncthreads();
        out[(size_t)(tn * 16 + ty) * K + tk * 16 + tx] = f2bf(s[tx][ty]);
        return;
    }
    if (bid >= 360) {                      // fragment-packed bias matrix
        int fb = bid - 360;                // (qt, T) major, h minor
        int qt = fb / 120;
        int rem = fb - qt * 120;
        int T = rem / 6, h = rem - (rem / 6) * 6;
        int tid = threadIdx.x;
        int half = tid >> 7, L = (tid >> 1) & 63, j4 = (tid & 1) * 4;
        int n = qt * 16 + (L & 15);
        int m = T * 64 + half * 32 + ((L >> 4) << 3) + j4;
        int4 iv = *(const int4*)(bidx + (size_t)n * LTOK + m);
        const float* tab = btab + (size_t)h * n_off;
        ushort4 o;
        o.x = f2bf(tab[iv.x] * L2E);
        o.y = f2bf(tab[iv.y] * L2E);
        o.z = f2bf(tab[iv.z] * L2E);
        o.w = f2bf(tab[iv.w] * L2E);
        *(ushort4*)(bmp + (size_t)(h * 80 + qt) * 20480 + T * 1024 + tid * 4) = o;
        return;
    }
    // ---- QKV GEMM: MTILE=256, K=192, N=576 ----
    int bx = bid % 9, by = bid / 9;
    int tid = threadIdx.x;
    int L = tid & 63, w = tid >> 6;
    int r = L & 15, g = L >> 4;
    int m0 = by * 256 + w * 64;
    int n0 = bx * 64;

    f32x4 acc[4][4] = {};
    const u16* Ab = A + (size_t)(m0 + r) * 192 + g * 8;
    const u16* Wb = Wt + (size_t)(n0 + r) * 192 + g * 8;
    #pragma unroll 6
    for (int k0 = 0; k0 < 192; k0 += 32) {
        s16x8 af[4];
        #pragma unroll
        for (int mi = 0; mi < 4; ++mi)
            af[mi] = *(const s16x8*)(Ab + (size_t)mi * 16 * 192 + k0);
        #pragma unroll
        for (int nn = 0; nn < 4; ++nn) {
            s16x8 bf = *(const s16x8*)(Wb + (size_t)nn * 16 * 192 + k0);
            #pragma unroll
            for (int mi = 0; mi < 4; ++mi)
                acc[mi][nn] = __builtin_amdgcn_mfma_f32_16x16x32_bf16(af[mi], bf, acc[mi][nn], 0, 0, 0);
        }
    }
    #pragma unroll
    for (int mi = 0; mi < 4; ++mi)
    #pragma unroll
    for (int nn = 0; nn < 4; ++nn) {
        int cb = n0 + nn * 16;
        int h  = cb / 96, c0 = cb % 96;
        int reg = c0 >> 5;                 // 0=q, 1=k, 2=v
        #pragma unroll
        for (int i = 0; i < 4; ++i) {
            int row = m0 + mi * 16 + g * 4 + i;
            float v = acc[mi][nn][i] + bias[cb + r];
            if (reg == 0) {
                v *= QS;
                qb[(size_t)row * DIMC + h * 32 + (c0 & 31) + r] = f2bf(v);
            } else {
                int b_ = row / LTOK, t = row - b_ * LTOK;
                int T = t >> 5, it = t & 31;
                int d = (c0 & 31) + r;
                if (reg == 1) {
                    int which = (it >> 2) & 1;
                    int ik = ((it >> 3) << 2) | (it & 3);
                    int Lk = ((d >> 3) << 4) + ik;
                    kp[((size_t)(b_ * HEADS + h) * 40 + T) * 1024 + which * 512 + Lk * 8 + (d & 7)] = f2bf(v);
                } else {
                    int Lv = ((it >> 3) << 4) + (d & 15);
                    vp[((size_t)(b_ * HEADS + h) * 40 + T) * 1024 + (d >> 4) * 512 + Lv * 8 + (it & 7)] = f2bf(v);
                }
            }
        }
    }
}

// ---------------- MFMA GEMM: C = act(A@W + bias) (+R)  --------------------
// A bf16 [M][K] row-major, Wt bf16 [N][K]. 256 thr = 4 waves.
template<int ACT, int RES, int OBF, int K, int MTILE>
__global__ __launch_bounds__(256) void gemm_mfma(const u16* __restrict__ A,
                                                 const u16* __restrict__ Wt,
                                                 const float* __restrict__ bias,
                                                 const float* __restrict__ R,
                                                 void* __restrict__ Cp,
                                                 int N) {
    constexpr int SUB = MTILE / 64;
    int tid = threadIdx.x;
    int L = tid & 63, w = tid >> 6;
    int r = L & 15, g = L >> 4;
    int m0 = blockIdx.y * MTILE + w * (16 * SUB);
    int n0 = blockIdx.x * 64;

    f32x4 acc[SUB][4] = {};
    const u16* Ab = A + (size_t)(m0 + r) * K + g * 8;
    const u16* Wb = Wt + (size_t)(n0 + r) * K + g * 8;
    #pragma unroll 6
    for (int k0 = 0; k0 < K; k0 += 32) {
        s16x8 af[SUB];
        #pragma unroll
        for (int mi = 0; mi < SUB; ++mi)
            af[mi] = *(const s16x8*)(Ab + (size_t)mi * 16 * K + k0);
        #pragma unroll
        for (int nn = 0; nn < 4; ++nn) {
            s16x8 bf = *(const s16x8*)(Wb + (size_t)nn * 16 * K + k0);
            #pragma unroll
            for (int mi = 0; mi < SUB; ++mi)
                acc[mi][nn] = __builtin_amdgcn_mfma_f32_16x16x32_bf16(af[mi], bf, acc[mi][nn], 0, 0, 0);
        }
    }

    #pragma unroll
    for (int mi = 0; mi < SUB; ++mi)
    #pragma unroll
    for (int nn = 0; nn < 4; ++nn) {
        int cb = n0 + nn * 16;
        #pragma unroll
        for (int i = 0; i < 4; ++i) {
            int row = m0 + mi * 16 + g * 4 + i;
            float v = acc[mi][nn][i] + bias[cb + r];
            if (ACT == 1) {
                float u = v;
                float y = 0.7978845608028654f * (u + 0.044715f * u * u * u);
                float e2 = fexp2(y * 2.885390081777927f);   // 2*log2(e)
                v = u - u * frcp(e2 + 1.0f);                // 0.5u(1+tanh(y))
            }
            if (RES) v += R[(size_t)row * N + cb + r];
            if (OBF) ((u16*)Cp)[(size_t)row * N + cb + r] = f2bf(v);
            else     ((float*)Cp)[(size_t)row * N + cb + r] = v;
        }
    }
}

// ---- MFMA flash attention: LDS K/V, 64-key iters, QK-ahead pipeline -------
__global__ __launch_bounds__(256) void attn_mfma(const u16* __restrict__ qb,
                                                 const u16* __restrict__ kp,
                                                 const u16* __restrict__ vp,
                                                 const u16* __restrict__ bmp,
                                                 u16* __restrict__ ob) {
    __shared__ __align__(16) u16 kvs[2][2][2048];   // [dbuf][k/v][2 tiles] 16KB
    int tid = threadIdx.x;
    int L = tid & 63, w = tid >> 6;
    int r = L & 15, g = L >> 4;
    int L8 = L * 8;

    int bid = blockIdx.x;
    int work = (bid & 7) * 120 + (bid >> 3);     // 960 = 8 * 120
    int b  = work & 7;
    int hq = work >> 3;                          // 0..119
    int qt = (hq % 20) * 4 + w;                  // 16-row q-tile, 0..79
    int h  = hq / 20;

    s16x8 qf = *(const s16x8*)(qb + (size_t)(b * LTOK + qt * 16 + r) * DIMC + h * 32 + g * 8);

    int skv = w >> 1, half = w & 1;
    const u16* gs = (skv ? vp : kp) + (size_t)(b * HEADS + h) * 40 * 1024 + L8;
    u16* dst0 = &kvs[0][skv][half * 1024 + L8];
    u16* dst1 = &kvs[1][skv][half * 1024 + L8];

    const u16* bmr = bmp + (size_t)(h * 80 + qt) * 20480 + L8;   // fragment-packed

    f32x4 acc0 = {0.f, 0.f, 0.f, 0.f}, acc1 = {0.f, 0.f, 0.f, 0.f};
    float lsum = 0.f;

    {
        int4 pA = *(const int4*)(gs + half * 1024);
        int4 pB = *(const int4*)(gs + half * 1024 + 512);
        *(int4*)dst0 = pA;
        *(int4*)(dst0 + 512) = pB;
    }
    int4 cb0 = *(const int4*)(bmr);
    int4 cb1 = *(const int4*)(bmr + 512);
    __syncthreads();

    f32x4 s0, s1, s2, s3;
    {
        const u16* kb = &kvs[0][0][0];
        f32x4 z0, z1, z2, z3;
        z0[0] = bflo(cb0.x); z0[1] = bfhi(cb0.x); z0[2] = bflo(cb0.y); z0[3] = bfhi(cb0.y);
        z1[0] = bflo(cb0.z); z1[1] = bfhi(cb0.z); z1[2] = bflo(cb0.w); z1[3] = bfhi(cb0.w);
        z2[0] = bflo(cb1.x); z2[1] = bfhi(cb1.x); z2[2] = bflo(cb1.y); z2[3] = bfhi(cb1.y);
        z3[0] = bflo(cb1.z); z3[1] = bfhi(cb1.z); z3[2] = bflo(cb1.w); z3[3] = bfhi(cb1.w);
        s16x8 kf0 = *(const s16x8*)(kb + L8);
        s16x8 kf1 = *(const s16x8*)(kb + 512 + L8);
        s16x8 kf2 = *(const s16x8*)(kb + 1024 + L8);
        s16x8 kf3 = *(const s16x8*)(kb + 1536 + L8);
        s0 = __builtin_amdgcn_mfma_f32_16x16x32_bf16(kf0, qf, z0, 0, 0, 0);
        s1 = __builtin_amdgcn_mfma_f32_16x16x32_bf16(kf1, qf, z1, 0, 0, 0);
        s2 = __builtin_amdgcn_mfma_f32_16x16x32_bf16(kf2, qf, z2, 0, 0, 0);
        s3 = __builtin_amdgcn_mfma_f32_16x16x32_bf16(kf3, qf, z3, 0, 0, 0);
    }

    #pragma unroll 1
    for (int T = 0; T < 20; ++T) {
        int4 nA, nB, nb0, nb1;
        if (T < 19) {
            nA  = *(const int4*)(gs + (size_t)(2 * T + 2 + half) * 1024);
            nB  = *(const int4*)(gs + (size_t)(2 * T + 2 + half) * 1024 + 512);
            nb0 = *(const int4*)(bmr + (size_t)(T + 1) * 1024);
            nb1 = *(const int4*)(bmr + (size_t)(T + 1) * 1024 + 512);
        }
        __builtin_amdgcn_s_setprio(1);
        float p[16];
        #pragma unroll
        for (int j = 0; j < 4; ++j) {
            p[j]      = fexp2(s0[j]);
            p[4 + j]  = fexp2(s1[j]);
            p[8 + j]  = fexp2(s2[j]);
            p[12 + j] = fexp2(s3[j]);
        }
        float t0 = ((p[0] + p[1]) + (p[2] + p[3])) + ((p[4] + p[5]) + (p[6] + p[7]));
        float t1 = ((p[8] + p[9]) + (p[10] + p[11])) + ((p[12] + p[13]) + (p[14] + p[15]));
        lsum += t0 + t1;
        union { unsigned u[4]; s16x8 v; } pa, pb;
        #pragma unroll
        for (int j = 0; j < 4; ++j) {
            asm("v_cvt_pk_bf16_f32 %0, %1, %2" : "=v"(pa.u[j]) : "v"(p[2 * j]), "v"(p[2 * j + 1]));
            asm("v_cvt_pk_bf16_f32 %0, %1, %2" : "=v"(pb.u[j]) : "v"(p[8 + 2 * j]), "v"(p[9 + 2 * j]));
        }
        const u16* vb = &kvs[T & 1][1][0];
        s16x8 v0 = *(const s16x8*)(vb + L8);
        s16x8 v1 = *(const s16x8*)(vb + 512 + L8);
        s16x8 v2 = *(const s16x8*)(vb + 1024 + L8);
        s16x8 v3 = *(const s16x8*)(vb + 1536 + L8);
        acc0 = __builtin_amdgcn_mfma_f32_16x16x32_bf16(pa.v, v0, acc0, 0, 0, 0);
        acc1 = __builtin_amdgcn_mfma_f32_16x16x32_bf16(pa.v, v1, acc1, 0, 0, 0);
        acc0 = __builtin_amdgcn_mfma_f32_16x16x32_bf16(pb.v, v2, acc0, 0, 0, 0);
        acc1 = __builtin_amdgcn_mfma_f32_16x16x32_bf16(pb.v, v3, acc1, 0, 0, 0);
        __builtin_amdgcn_s_setprio(0);

        if (T < 19) {
            u16* d = (T & 1) ? dst0 : dst1;      // buf[(T+1)&1]
            *(int4*)d = nA;
            *(int4*)(d + 512) = nB;
        }
        __syncthreads();
        if (T < 19) {
            const u16* kb = &kvs[(T + 1) & 1][0][0];
            f32x4 z0, z1, z2, z3;
            z0[0] = bflo(nb0.x); z0[1] = bfhi(nb0.x); z0[2] = bflo(nb0.y); z0[3] = bfhi(nb0.y);
            z1[0] = bflo(nb0.z); z1[1] = bfhi(nb0.z); z1[2] = bflo(nb0.w); z1[3] = bfhi(nb0.w);
            z2[0] = bflo(nb1.x); z2[1] = bfhi(nb1.x); z2[2] = bflo(nb1.y); z2[3] = bfhi(nb1.y);
            z3[0] = bflo(nb1.z); z3[1] = bfhi(nb1.z); z3[2] = bflo(nb1.w); z3[3] = bfhi(nb1.w);
            s16x8 kf0 = *(const s16x8*)(kb + L8);
            s16x8 kf1 = *(const s16x8*)(kb + 512 + L8);
            s16x8 kf2 = *(const s16x8*)(kb + 1024 + L8);
            s16x8 kf3 = *(const s16x8*)(kb + 1536 + L8);
            __builtin_amdgcn_s_setprio(1);
            s0 = __builtin_amdgcn_mfma_f32_16x16x32_bf16(kf0, qf, z0, 0, 0, 0);
            s1 = __builtin_amdgcn_mfma_f32_16x16x32_bf16(kf1, qf, z1, 0, 0, 0);
            s2 = __builtin_amdgcn_mfma_f32_16x16x32_bf16(kf2, qf, z2, 0, 0, 0);
            s3 = __builtin_amdgcn_mfma_f32_16x16x32_bf16(kf3, qf, z3, 0, 0, 0);
            __builtin_amdgcn_s_setprio(0);
        }
    }

    float lr = lsum;
    lr += __shfl_xor(lr, 16);
    lr += __shfl_xor(lr, 32);
    #pragma unroll
    for (int i = 0; i < 4; ++i) {
        float linv = frcp(__shfl(lr, 4 * g + i));
        size_t orow = (size_t)(b * LTOK + qt * 16 + 4 * g + i) * DIMC + h * 32 + r;
        ob[orow]      = f2bf(acc0[i] * linv);
        ob[orow + 16] = f2bf(acc1[i] * linv);
    }
}

// ------- Depthwise 3x3 conv + BN + LayerNorm2 fused (wave per row) ---------
__global__ __launch_bounds__(256) void conv_ln_kernel(const float* __restrict__ xm,
                                                      const float* __restrict__ w,
                                                      const float* __restrict__ scale,
                                                      const float* __restrict__ bias,
                                                      const float* __restrict__ g2,
                                                      const float* __restrict__ b2,
                                                      float* __restrict__ xm2,
                                                      u16* __restrict__ y) {
    int row = blockIdx.x * 4 + (threadIdx.x >> 6);
    int lane = threadIdx.x & 63;
    int b = row / LTOK, t = row - b * LTOK;
    int H, W, base, y0, x0;
    if (t < 1024) { H = 32; W = 32; base = 0;    y0 = t >> 5;            x0 = t & 31; }
    else          { H = 16; W = 16; base = 1024; int tt = t - 1024; y0 = tt >> 4; x0 = tt & 15; }
    float a0 = 0.f, a1 = 0.f, a2 = 0.f;
    #pragma unroll
    for (int ky = 0; ky < 3; ++ky) {
        int yy = y0 + ky - 1;
        if (yy < 0 || yy >= H) continue;
        #pragma unroll
        for (int kx = 0; kx < 3; ++kx) {
            int xx = x0 + kx - 1;
            if (xx < 0 || xx >= W) continue;
            const float* xr = xm + (size_t)(b * LTOK + base + yy * W + xx) * DIMC;
            const float* wr = w + (ky * 3 + kx) * DIMC;
            a0 += wr[lane]       * xr[lane];
            a1 += wr[lane + 64]  * xr[lane + 64];
            a2 += wr[lane + 128] * xr[lane + 128];
        }
    }
    float v0 = a0 * scale[lane]       + bias[lane];
    float v1 = a1 * scale[lane + 64]  + bias[lane + 64];
    float v2 = a2 * scale[lane + 128] + bias[lane + 128];
    float* xr2 = xm2 + (size_t)row * DIMC;
    xr2[lane] = v0; xr2[lane + 64] = v1; xr2[lane + 128] = v2;
    float s = v0 + v1 + v2;
    float ss = v0 * v0 + v1 * v1 + v2 * v2;
    #pragma unroll
    for (int off = 32; off; off >>= 1) {
        s  += __shfl_xor(s, off);
        ss += __shfl_xor(ss, off);
    }
    float mu  = s * (1.0f / DIMC);
    float var = ss * (1.0f / DIMC) - mu * mu;
    float inv = rsqrtf(var + 1e-5f);
    u16* yr = y + (size_t)row * DIMC;
    yr[lane]       = f2bf((v0 - mu) * inv * g2[lane]       + b2[lane]);
    yr[lane + 64]  = f2bf((v1 - mu) * inv * g2[lane + 64]  + b2[lane + 64]);
    yr[lane + 128] = f2bf((v2 - mu) * inv * g2[lane + 128] + b2[lane + 128]);
}

// ---------------------------------------------------------------------------
extern "C" void kernel_launch(void* const* d_in, const int* in_sizes, int n_in,
                              void* d_out, int out_size, void* d_ws, size_t ws_size,
                              hipStream_t stream) {
    const float* xz       = (const float*)d_in[0];
    const int*   bidx     = (const int*)  d_in[1];
    const float* ln1_g    = (const float*)d_in[2];
    const float* ln1_b    = (const float*)d_in[3];
    const float* wqkv     = (const float*)d_in[4];
    const float* bqkv     = (const float*)d_in[5];
    const float* wproj    = (const float*)d_in[6];
    const float* bproj    = (const float*)d_in[7];
    const float* btab     = (const float*)d_in[8];
    const float* conv_w   = (const float*)d_in[9];
    const float* bn_scale = (const float*)d_in[10];
    const float* bn_bias  = (const float*)d_in[11];
    const float* ln2_g    = (const float*)d_in[12];
    const float* ln2_b    = (const float*)d_in[13];
    const float* w1       = (const float*)d_in[14];
    const float* b1       = (const float*)d_in[15];
    const float* w2       = (const float*)d_in[16];
    const float* b2       = (const float*)d_in[17];
    int n_off = in_sizes[8] / HEADS;
    float* out = (float*)d_out;

    // ---- workspace layout (bytes), liveness overlays; peak 40.2 MB ----
    char* wsb = (char*)d_ws;
    u16*  hbuf   = (u16*)(wsb + 0);                    // ln out; ob overlays
    u16*  ob     = (u16*)(wsb + 0);
    u16*  wqkvT  = (u16*)(wsb + 3932160);
    u16*  wprojT = (u16*)(wsb + 4153344);
    u16*  w1T    = (u16*)(wsb + 4227072);
    u16*  w2T    = (u16*)(wsb + 4521984);
    u16*  bmp    = (u16*)(wsb + 4816896);              // 19.6 MB; hid overlays
    u16*  hid    = (u16*)(wsb + 4816896);
    u16*  kp     = (u16*)(wsb + 24477696);
    u16*  vp     = (u16*)(wsb + 28409856);
    float* xm2   = (float*)(wsb + 24477696);           // overlays kp/vp
    u16*  qb     = (u16*)(wsb + 32342016);
    float* xm    = (float*)(wsb + 32342016);           // overlays qb

    // 1) minimal critical-path prefix: wqkv transpose + LN1
    pre_a<<<432 + NROWS / 4, 256, 0, stream>>>(wqkv, wqkvT, xz, ln1_g, ln1_b, hbuf);
    // 2) QKV GEMM + bias-matrix pack + late weight transposes (one launch)
    qkv_mega<<<11256, 256, 0, stream>>>(
        hbuf, wqkvT, bqkv, qb, kp, vp,
        bidx, btab, n_off, bmp,
        wproj, w1, w2, wprojT, w1T, w2T);
    // 3) attention (QK-ahead pipeline, dbuf LDS, XCD-swizzled)
    attn_mfma<<<960, 256, 0, stream>>>(qb, kp, vp, bmp, ob);
    // 4) proj + residual(xz) -> xm f32
    gemm_mfma<0,1,0,DIMC,128><<<dim3(DIMC / 64, NROWS / 128), 256, 0, stream>>>(
        ob, wprojT, bproj, xz, xm, DIMC);
    // 5) depthwise conv + BN + LN2 -> xm2 f32 + hbuf bf16
    conv_ln_kernel<<<NROWS / 4, 256, 0, stream>>>(
        xm, conv_w, bn_scale, bn_bias, ln2_g, ln2_b, xm2, hbuf);
    // 6) MLP fc1 + GELU (MTILE=256) -> hid bf16
    gemm_mfma<1,0,1,DIMC,256><<<dim3(HID / 64, NROWS / 256), 256, 0, stream>>>(
        hbuf, w1T, b1, nullptr, hid, HID);
    // 7) MLP fc2 + residual(xm2) -> out f32
    gemm_mfma<0,1,0,HID,128><<<dim3(DIMC / 64, NROWS / 128), 256, 0, stream>>>(
        hid, w2T, b2, xm2, out, DIMC);
}